// Round 1
// baseline (2799.403 us; speedup 1.0000x reference)
//
#include <hip/hip_runtime.h>
#include <math.h>

// ---------------------------------------------------------------------------
// Decoder_82764019794508: LIIF-style decoder, fp32 baseline.
// Pipeline:
//   K0  prep_weights : transpose mw0 (102x64)->w0T (64x102), mw1->w1T (64x64)
//   K1  conv1x1 feats4  (2,96,96,96)  -> a4s  (2,96,96,32)   +ReLU
//   K2  conv1x1 feats32 (2,24,24,160) -> a32s (2,24,24,32)   +ReLU
//   K3a conv1x1 feats2  (2,192,192,64)-> xcat[...,0:32]      +ReLU
//   K3b bilinear upsample a4s  -> xcat[...,32:64]
//   K3c bilinear upsample a32s -> xcat[...,64:96]
//   K4  conv3x3 (96->96) + bias + ReLU -> aspp (2,192,192,96)
//   K5  4-corner nearest gather + MLP(102->64->64->1) ensemble -> out
// ---------------------------------------------------------------------------

#define HQ 384
#define HA 192

// ---- K0: pack/transpose MLP weights ---------------------------------------
__global__ void prep_weights(const float* __restrict__ mw0,
                             const float* __restrict__ mw1,
                             float* __restrict__ w0T, float* __restrict__ w1T) {
    int t = blockIdx.x * blockDim.x + threadIdx.x;
    int stride = gridDim.x * blockDim.x;
    for (int idx = t; idx < 64 * 102; idx += stride) {
        int j = idx / 102, i = idx - j * 102;
        w0T[idx] = mw0[i * 64 + j];
    }
    for (int idx = t; idx < 64 * 64; idx += stride) {
        int j = idx >> 6, i = idx & 63;
        w1T[idx] = mw1[i * 64 + j];
    }
}

// ---- K1/K2: 1x1 conv + ReLU, CIN -> 32, contiguous output -----------------
template <int CIN>
__global__ void conv1x1_relu(const float* __restrict__ x,
                             const float* __restrict__ w,
                             const float* __restrict__ b,
                             float* __restrict__ y, int npix) {
    int t = blockIdx.x * blockDim.x + threadIdx.x;
    int p = t >> 5, c = t & 31;
    if (p >= npix) return;
    const float* xr = x + (size_t)p * CIN;
    float acc = b[c];
#pragma unroll
    for (int i = 0; i < CIN; ++i) acc = fmaf(xr[i], w[i * 32 + c], acc);
    y[(size_t)p * 32 + c] = fmaxf(acc, 0.f);
}

// ---- K3a: 1x1 conv (64->32) + ReLU writing into 96-ch concat buffer -------
__global__ void conv1x1_relu_into96(const float* __restrict__ x,
                                    const float* __restrict__ w,
                                    const float* __restrict__ b,
                                    float* __restrict__ y, int npix) {
    int t = blockIdx.x * blockDim.x + threadIdx.x;
    int p = t >> 5, c = t & 31;
    if (p >= npix) return;
    const float* xr = x + (size_t)p * 64;
    float acc = b[c];
#pragma unroll
    for (int i = 0; i < 64; ++i) acc = fmaf(xr[i], w[i * 32 + c], acc);
    y[(size_t)p * 96 + c] = fmaxf(acc, 0.f);
}

// ---- K3b/K3c: bilinear upsample (half-pixel centers, edge-clamped) --------
// src: (2, S, S, 32), dst: xcat channel slice [coff, coff+32)
__global__ void upsample_into96(const float* __restrict__ src,
                                float* __restrict__ dst,
                                int S, float inv, int coff) {
    int t = blockIdx.x * blockDim.x + threadIdx.x;
    const int total = 2 * HA * HA * 32;
    if (t >= total) return;
    int c = t & 31;
    int r = t >> 5;
    int x = r % HA; r /= HA;
    int y = r % HA; int b = r / HA;

    float u = ((float)y + 0.5f) * inv - 0.5f;
    float v = ((float)x + 0.5f) * inv - 0.5f;
    float fu = floorf(u), fv = floorf(v);
    float wu = u - fu, wv = v - fv;
    int y0 = (int)fu, x0 = (int)fv;
    int y1 = min(y0 + 1, S - 1);
    int x1 = min(x0 + 1, S - 1);
    y0 = max(y0, 0);
    x0 = max(x0, 0);

    const float* sb = src + (size_t)b * S * S * 32 + c;
    float v00 = sb[(y0 * S + x0) * 32];
    float v01 = sb[(y0 * S + x1) * 32];
    float v10 = sb[(y1 * S + x0) * 32];
    float v11 = sb[(y1 * S + x1) * 32];
    float t0 = v00 * (1.f - wu) + v10 * wu;
    float t1 = v01 * (1.f - wu) + v11 * wu;
    float o  = t0 * (1.f - wv) + t1 * wv;
    dst[(((size_t)b * HA + y) * HA + x) * 96 + coff + c] = o;
}

// ---- K4: 3x3 conv 96->96 + bias + ReLU, zero ("SAME") padding -------------
// block = 16x16 pixels, each thread computes all 96 output channels.
// Input channels processed in 6 chunks of 16 staged through LDS [ci][y][x].
__launch_bounds__(256)
__global__ void conv3x3_relu(const float* __restrict__ x,
                             const float* __restrict__ w,
                             const float* __restrict__ bias,
                             float* __restrict__ y) {
    __shared__ float lds[16 * 18 * 18];  // 20.7 KB
    const int tx = threadIdx.x, ty = threadIdx.y;
    const int bx = blockIdx.x * 16, by = blockIdx.y * 16;
    const int b = blockIdx.z;
    const int tid = ty * 16 + tx;

    float acc[96];
#pragma unroll
    for (int co = 0; co < 96; ++co) acc[co] = 0.f;

    for (int chunk = 0; chunk < 6; ++chunk) {
        __syncthreads();
        for (int idx = tid; idx < 16 * 18 * 18; idx += 256) {
            int i = idx & 15;
            int pos = idx >> 4;
            int lx = pos % 18;
            int ly = pos / 18;
            int gy = by + ly - 1, gx = bx + lx - 1;
            float v = 0.f;
            if (gy >= 0 && gy < HA && gx >= 0 && gx < HA)
                v = x[(((size_t)b * HA + gy) * HA + gx) * 96 + chunk * 16 + i];
            lds[i * 324 + ly * 18 + lx] = v;
        }
        __syncthreads();
#pragma unroll
        for (int ky = 0; ky < 3; ++ky)
#pragma unroll
            for (int kx = 0; kx < 3; ++kx)
                for (int i = 0; i < 16; ++i) {
                    float v = lds[i * 324 + (ty + ky) * 18 + (tx + kx)];
                    const float* wr = w + ((ky * 3 + kx) * 96 + chunk * 16 + i) * 96;
#pragma unroll
                    for (int co = 0; co < 96; ++co)
                        acc[co] = fmaf(v, wr[co], acc[co]);
                }
    }

    float* yp = y + (((size_t)b * HA + by + ty) * HA + bx + tx) * 96;
#pragma unroll
    for (int q = 0; q < 24; ++q) {
        float4 o;
        o.x = fmaxf(acc[q * 4 + 0] + bias[q * 4 + 0], 0.f);
        o.y = fmaxf(acc[q * 4 + 1] + bias[q * 4 + 1], 0.f);
        o.z = fmaxf(acc[q * 4 + 2] + bias[q * 4 + 2], 0.f);
        o.w = fmaxf(acc[q * 4 + 3] + bias[q * 4 + 3], 0.f);
        ((float4*)yp)[q] = o;
    }
}

// ---- K5: 4-corner gather + MLP ensemble -----------------------------------
__launch_bounds__(256)
__global__ void decoder_mlp(const float* __restrict__ aspp,
                            const float* __restrict__ coords,
                            const float* __restrict__ cells,
                            const float* __restrict__ w0T,
                            const float* __restrict__ mb0,
                            const float* __restrict__ w1T,
                            const float* __restrict__ mb1,
                            const float* __restrict__ mw2,
                            const float* __restrict__ mb2,
                            float* __restrict__ out) {
    const int t = blockIdx.x * 256 + threadIdx.x;  // exact grid: 2*384*384
    const int b = t / (HQ * HQ);

    const float cy = coords[(size_t)t * 2 + 0];
    const float cx = coords[(size_t)t * 2 + 1];
    const float rcy = cells[(size_t)t * 2 + 0] * (float)HA;
    const float rcx = cells[(size_t)t * 2 + 1] * (float)HA;

    const float LO = -1.0f + 1e-7f, HI = 1.0f - 1e-7f;
    const float RXY = 1.0f / (float)HA;

    float preds[4], areas[4];

#pragma unroll
    for (int k = 0; k < 4; ++k) {
        const float vy = (k < 2) ? -1.f : 1.f;
        const float vx = (k & 1) ? 1.f : -1.f;

        float c0 = fminf(fmaxf((cy + vy * RXY) + 1e-7f, LO), HI);
        float c1 = fminf(fmaxf((cx + vx * RXY) + 1e-7f, LO), HI);
        // i = round_half_even((c+1)*192/2 - 0.5), clipped
        int iy = (int)rintf(((c0 + 1.f) * (float)HA) * 0.5f - 0.5f);
        int ix = (int)rintf(((c1 + 1.f) * (float)HA) * 0.5f - 0.5f);
        iy = min(max(iy, 0), HA - 1);
        ix = min(max(ix, 0), HA - 1);

        float cs0 = (((float)iy + 0.5f) / (float)HA) * 2.f - 1.f;
        float cs1 = (((float)ix + 0.5f) / (float)HA) * 2.f - 1.f;
        float r0 = (cy - cs0) * (float)HA;
        float r1 = (cx - cs1) * (float)HA;
        areas[k] = fabsf(r0 * r1) + 1e-7f;

        const float* fp = aspp + (((size_t)b * HA + iy) * HA + ix) * 96;
        float in[102];
#pragma unroll
        for (int q = 0; q < 24; ++q) {
            float4 v = ((const float4*)fp)[q];
            in[q * 4 + 0] = v.x;
            in[q * 4 + 1] = v.y;
            in[q * 4 + 2] = v.z;
            in[q * 4 + 3] = v.w;
        }
        in[96] = r0; in[97] = r1;
        in[98] = cy; in[99] = cx;
        in[100] = rcy; in[101] = rcx;

        float h0[64];
#pragma unroll 2
        for (int j = 0; j < 64; ++j) {
            const float* wr = w0T + j * 102;
            float acc = mb0[j];
#pragma unroll
            for (int i = 0; i < 102; ++i) acc = fmaf(in[i], wr[i], acc);
            h0[j] = fmaxf(acc, 0.f);
        }

        float h1[64];
#pragma unroll 2
        for (int j = 0; j < 64; ++j) {
            const float* wr = w1T + j * 64;
            float acc = mb1[j];
#pragma unroll
            for (int i = 0; i < 64; ++i) acc = fmaf(h0[i], wr[i], acc);
            h1[j] = fmaxf(acc, 0.f);
        }

        float acc = mb2[0];
#pragma unroll
        for (int i = 0; i < 64; ++i) acc = fmaf(h1[i], mw2[i], acc);
        preds[k] = acc;
    }

    // areas list was built with insert(0): pred_k pairs with area_{3-k}
    float num = preds[0] * areas[3] + preds[1] * areas[2] +
                preds[2] * areas[1] + preds[3] * areas[0];
    float den = areas[0] + areas[1] + areas[2] + areas[3];
    out[t] = num / den;
}

// ---------------------------------------------------------------------------
extern "C" void kernel_launch(void* const* d_in, const int* in_sizes, int n_in,
                              void* d_out, int out_size, void* d_ws, size_t ws_size,
                              hipStream_t stream) {
    (void)in_sizes; (void)n_in; (void)out_size; (void)ws_size;
    const float* feats2  = (const float*)d_in[0];
    const float* feats4  = (const float*)d_in[1];
    const float* feats32 = (const float*)d_in[2];
    const float* coords  = (const float*)d_in[3];
    const float* cells   = (const float*)d_in[4];
    const float* w2  = (const float*)d_in[5];
    const float* b2  = (const float*)d_in[6];
    const float* w4  = (const float*)d_in[7];
    const float* b4  = (const float*)d_in[8];
    const float* w32 = (const float*)d_in[9];
    const float* b32 = (const float*)d_in[10];
    const float* wf  = (const float*)d_in[11];
    const float* bf  = (const float*)d_in[12];
    const float* mw0 = (const float*)d_in[13];
    const float* mb0 = (const float*)d_in[14];
    const float* mw1 = (const float*)d_in[15];
    const float* mb1 = (const float*)d_in[16];
    const float* mw2 = (const float*)d_in[17];
    const float* mb2 = (const float*)d_in[18];

    float* ws   = (float*)d_ws;
    float* a4s  = ws;                   // 2*96*96*32   = 589824
    float* a32s = a4s  + 589824;        // 2*24*24*32   = 36864
    float* xcat = a32s + 36864;         // 2*192*192*96 = 7077888
    float* aspp = xcat + 7077888;       // 7077888
    float* w0T  = aspp + 7077888;       // 64*102 = 6528
    float* w1T  = w0T  + 6528;          // 64*64  = 4096
    float* out  = (float*)d_out;

    prep_weights<<<26, 256, 0, stream>>>(mw0, mw1, w0T, w1T);
    conv1x1_relu<96><<<2304, 256, 0, stream>>>(feats4, w4, b4, a4s, 2 * 96 * 96);
    conv1x1_relu<160><<<144, 256, 0, stream>>>(feats32, w32, b32, a32s, 2 * 24 * 24);
    conv1x1_relu_into96<<<9216, 256, 0, stream>>>(feats2, w2, b2, xcat, 2 * HA * HA);
    upsample_into96<<<9216, 256, 0, stream>>>(a4s, xcat, 96, 0.5f, 32);
    upsample_into96<<<9216, 256, 0, stream>>>(a32s, xcat, 24, 0.125f, 64);
    conv3x3_relu<<<dim3(12, 12, 2), dim3(16, 16), 0, stream>>>(xcat, wf, bf, aspp);
    decoder_mlp<<<1152, 256, 0, stream>>>(aspp, coords, cells, w0T, mb0,
                                          w1T, mb1, mw2, mb2, out);
}

// Round 2
// 1237.877 us; speedup vs baseline: 2.2615x; 2.2615x over previous
//
#include <hip/hip_runtime.h>
#include <math.h>

// ---------------------------------------------------------------------------
// Decoder_82764019794508: LIIF-style decoder, fp32.
// R2: decoder_mlp rewritten to kill scratch spills (R1: 589MB spill writes).
//   - layer0 i-outer/j-inner, features streamed via float4 double-buffer
//   - weights accessed with wave-uniform addresses -> scalar loads
//   - layer1+layer2 fused, no h1 array; h0[64] is the only big register set
// ---------------------------------------------------------------------------

#define HQ 384
#define HA 192

// ---- K0: transpose mw1 (64x64) -> w1T so layer1 rows are contiguous -------
__global__ void prep_weights(const float* __restrict__ mw1,
                             float* __restrict__ w1T) {
    int t = blockIdx.x * blockDim.x + threadIdx.x;
    if (t < 64 * 64) {
        int j = t >> 6, i = t & 63;
        w1T[t] = mw1[i * 64 + j];  // w1T[j][i] = mw1[i][j]
    }
}

// ---- K1/K2: 1x1 conv + ReLU, CIN -> 32, contiguous output -----------------
template <int CIN>
__global__ void conv1x1_relu(const float* __restrict__ x,
                             const float* __restrict__ w,
                             const float* __restrict__ b,
                             float* __restrict__ y, int npix) {
    int t = blockIdx.x * blockDim.x + threadIdx.x;
    int p = t >> 5, c = t & 31;
    if (p >= npix) return;
    const float* xr = x + (size_t)p * CIN;
    float acc = b[c];
#pragma unroll
    for (int i = 0; i < CIN; ++i) acc = fmaf(xr[i], w[i * 32 + c], acc);
    y[(size_t)p * 32 + c] = fmaxf(acc, 0.f);
}

// ---- K3a: 1x1 conv (64->32) + ReLU writing into 96-ch concat buffer -------
__global__ void conv1x1_relu_into96(const float* __restrict__ x,
                                    const float* __restrict__ w,
                                    const float* __restrict__ b,
                                    float* __restrict__ y, int npix) {
    int t = blockIdx.x * blockDim.x + threadIdx.x;
    int p = t >> 5, c = t & 31;
    if (p >= npix) return;
    const float* xr = x + (size_t)p * 64;
    float acc = b[c];
#pragma unroll
    for (int i = 0; i < 64; ++i) acc = fmaf(xr[i], w[i * 32 + c], acc);
    y[(size_t)p * 96 + c] = fmaxf(acc, 0.f);
}

// ---- K3b/K3c: bilinear upsample (half-pixel centers, edge-clamped) --------
__global__ void upsample_into96(const float* __restrict__ src,
                                float* __restrict__ dst,
                                int S, float inv, int coff) {
    int t = blockIdx.x * blockDim.x + threadIdx.x;
    const int total = 2 * HA * HA * 32;
    if (t >= total) return;
    int c = t & 31;
    int r = t >> 5;
    int x = r % HA; r /= HA;
    int y = r % HA; int b = r / HA;

    float u = ((float)y + 0.5f) * inv - 0.5f;
    float v = ((float)x + 0.5f) * inv - 0.5f;
    float fu = floorf(u), fv = floorf(v);
    float wu = u - fu, wv = v - fv;
    int y0 = (int)fu, x0 = (int)fv;
    int y1 = min(y0 + 1, S - 1);
    int x1 = min(x0 + 1, S - 1);
    y0 = max(y0, 0);
    x0 = max(x0, 0);

    const float* sb = src + (size_t)b * S * S * 32 + c;
    float v00 = sb[(y0 * S + x0) * 32];
    float v01 = sb[(y0 * S + x1) * 32];
    float v10 = sb[(y1 * S + x0) * 32];
    float v11 = sb[(y1 * S + x1) * 32];
    float t0 = v00 * (1.f - wu) + v10 * wu;
    float t1 = v01 * (1.f - wu) + v11 * wu;
    float o  = t0 * (1.f - wv) + t1 * wv;
    dst[(((size_t)b * HA + y) * HA + x) * 96 + coff + c] = o;
}

// ---- K4: 3x3 conv 96->96 + bias + ReLU, zero ("SAME") padding -------------
__launch_bounds__(256)
__global__ void conv3x3_relu(const float* __restrict__ x,
                             const float* __restrict__ w,
                             const float* __restrict__ bias,
                             float* __restrict__ y) {
    __shared__ float lds[16 * 18 * 18];  // 20.7 KB
    const int tx = threadIdx.x, ty = threadIdx.y;
    const int bx = blockIdx.x * 16, by = blockIdx.y * 16;
    const int b = blockIdx.z;
    const int tid = ty * 16 + tx;

    float acc[96];
#pragma unroll
    for (int co = 0; co < 96; ++co) acc[co] = 0.f;

    for (int chunk = 0; chunk < 6; ++chunk) {
        __syncthreads();
        for (int idx = tid; idx < 16 * 18 * 18; idx += 256) {
            int i = idx & 15;
            int pos = idx >> 4;
            int lx = pos % 18;
            int ly = pos / 18;
            int gy = by + ly - 1, gx = bx + lx - 1;
            float v = 0.f;
            if (gy >= 0 && gy < HA && gx >= 0 && gx < HA)
                v = x[(((size_t)b * HA + gy) * HA + gx) * 96 + chunk * 16 + i];
            lds[i * 324 + ly * 18 + lx] = v;
        }
        __syncthreads();
#pragma unroll
        for (int ky = 0; ky < 3; ++ky)
#pragma unroll
            for (int kx = 0; kx < 3; ++kx)
                for (int i = 0; i < 16; ++i) {
                    float v = lds[i * 324 + (ty + ky) * 18 + (tx + kx)];
                    const float* wr = w + ((ky * 3 + kx) * 96 + chunk * 16 + i) * 96;
#pragma unroll
                    for (int co = 0; co < 96; ++co)
                        acc[co] = fmaf(v, wr[co], acc[co]);
                }
    }

    float* yp = y + (((size_t)b * HA + by + ty) * HA + bx + tx) * 96;
#pragma unroll
    for (int q = 0; q < 24; ++q) {
        float4 o;
        o.x = fmaxf(acc[q * 4 + 0] + bias[q * 4 + 0], 0.f);
        o.y = fmaxf(acc[q * 4 + 1] + bias[q * 4 + 1], 0.f);
        o.z = fmaxf(acc[q * 4 + 2] + bias[q * 4 + 2], 0.f);
        o.w = fmaxf(acc[q * 4 + 3] + bias[q * 4 + 3], 0.f);
        ((float4*)yp)[q] = o;
    }
}

// ---- K5: 4-corner gather + MLP ensemble (spill-free restructure) ----------
// Per thread = one query pixel. Corner loop dynamic. Layer0: stream 96 feats
// via float4 dbuf, 64 FMAs per element into h[64] (weights = uniform scalar
// rows of native mw0). Layer1+2 fused: per uniform j, 64 reg-FMAs against
// contiguous w1T row, fold relu(h1_j)*mw2[j] into pred immediately.
__launch_bounds__(256)
__global__ void decoder_mlp(const float* __restrict__ aspp,
                            const float* __restrict__ coords,
                            const float* __restrict__ cells,
                            const float* __restrict__ mw0,
                            const float* __restrict__ mb0,
                            const float* __restrict__ w1T,
                            const float* __restrict__ mb1,
                            const float* __restrict__ mw2,
                            const float* __restrict__ mb2,
                            float* __restrict__ out) {
    const int t = blockIdx.x * 256 + threadIdx.x;  // exact grid: 2*384*384
    const int b = t / (HQ * HQ);

    const float cy = coords[(size_t)t * 2 + 0];
    const float cx = coords[(size_t)t * 2 + 1];
    const float rcy = cells[(size_t)t * 2 + 0] * (float)HA;
    const float rcx = cells[(size_t)t * 2 + 1] * (float)HA;

    const float LO = -1.0f + 1e-7f, HI = 1.0f - 1e-7f;
    const float RXY = 1.0f / (float)HA;

    // ---- precompute all 4 corners: packed indices + areas ----
    unsigned iyp = 0, ixp = 0;
    float a0, a1, a2, a3;
    float den = 0.f;
#pragma unroll
    for (int k = 0; k < 4; ++k) {
        const float vy = (k < 2) ? -1.f : 1.f;
        const float vx = (k & 1) ? 1.f : -1.f;
        float c0 = fminf(fmaxf((cy + vy * RXY) + 1e-7f, LO), HI);
        float c1 = fminf(fmaxf((cx + vx * RXY) + 1e-7f, LO), HI);
        int iy = (int)rintf(((c0 + 1.f) * (float)HA) * 0.5f - 0.5f);
        int ix = (int)rintf(((c1 + 1.f) * (float)HA) * 0.5f - 0.5f);
        iy = min(max(iy, 0), HA - 1);
        ix = min(max(ix, 0), HA - 1);
        iyp |= (unsigned)iy << (8 * k);
        ixp |= (unsigned)ix << (8 * k);
        float cs0 = (((float)iy + 0.5f) / (float)HA) * 2.f - 1.f;
        float cs1 = (((float)ix + 0.5f) / (float)HA) * 2.f - 1.f;
        float r0 = (cy - cs0) * (float)HA;
        float r1 = (cx - cs1) * (float)HA;
        float a = fabsf(r0 * r1) + 1e-7f;
        if (k == 0) a0 = a; else if (k == 1) a1 = a;
        else if (k == 2) a2 = a; else a3 = a;
        den += a;
    }

    float h[64];
    float num = 0.f;

    auto l0row = [&](float v, int row) {
        const float* wr = mw0 + row * 64;
#pragma unroll
        for (int j = 0; j < 64; ++j) h[j] = fmaf(v, wr[j], h[j]);
    };

#pragma unroll 1
    for (int k = 0; k < 4; ++k) {
        const int iy = (iyp >> (8 * k)) & 255;
        const int ix = (ixp >> (8 * k)) & 255;
        const float cs0 = (((float)iy + 0.5f) / (float)HA) * 2.f - 1.f;
        const float cs1 = (((float)ix + 0.5f) / (float)HA) * 2.f - 1.f;
        const float r0 = (cy - cs0) * (float)HA;
        const float r1 = (cx - cs1) * (float)HA;

        const float4* fp4 =
            (const float4*)(aspp + (((size_t)b * HA + iy) * HA + ix) * 96);

        // init accumulators with bias
#pragma unroll
        for (int j = 0; j < 64; ++j) h[j] = mb0[j];

        // ---- layer0: stream 24 float4 feature chunks (double-buffered) ----
        float4 u0 = fp4[0];
        float4 u1 = fp4[1];
#pragma unroll 1
        for (int q = 0; q < 24; q += 2) {
            float4 ca = u0;
            if (q + 2 < 24) u0 = fp4[q + 2];
            l0row(ca.x, 4 * q + 0);
            l0row(ca.y, 4 * q + 1);
            l0row(ca.z, 4 * q + 2);
            l0row(ca.w, 4 * q + 3);
            float4 cb = u1;
            if (q + 3 < 24) u1 = fp4[q + 3];
            l0row(cb.x, 4 * q + 4);
            l0row(cb.y, 4 * q + 5);
            l0row(cb.z, 4 * q + 6);
            l0row(cb.w, 4 * q + 7);
        }
        // extras: rel(2), coords(2), rel_cells(2)
        l0row(r0, 96);
        l0row(r1, 97);
        l0row(cy, 98);
        l0row(cx, 99);
        l0row(rcy, 100);
        l0row(rcx, 101);

#pragma unroll
        for (int j = 0; j < 64; ++j) h[j] = fmaxf(h[j], 0.f);

        // ---- layer1 + layer2 fused ----
        float pred = mb2[0];
#pragma unroll 1
        for (int j = 0; j < 64; ++j) {
            const float* wr = w1T + j * 64;
            float acc = mb1[j];
#pragma unroll
            for (int i = 0; i < 64; ++i) acc = fmaf(h[i], wr[i], acc);
            pred = fmaf(fmaxf(acc, 0.f), mw2[j], pred);
        }

        // pred_k pairs with area_{3-k} (reference's areas.insert(0, ...))
        float apair = (k == 0) ? a3 : ((k == 1) ? a2 : ((k == 2) ? a1 : a0));
        num = fmaf(pred, apair, num);
    }

    out[t] = num / den;
}

// ---------------------------------------------------------------------------
extern "C" void kernel_launch(void* const* d_in, const int* in_sizes, int n_in,
                              void* d_out, int out_size, void* d_ws, size_t ws_size,
                              hipStream_t stream) {
    (void)in_sizes; (void)n_in; (void)out_size; (void)ws_size;
    const float* feats2  = (const float*)d_in[0];
    const float* feats4  = (const float*)d_in[1];
    const float* feats32 = (const float*)d_in[2];
    const float* coords  = (const float*)d_in[3];
    const float* cells   = (const float*)d_in[4];
    const float* w2  = (const float*)d_in[5];
    const float* b2  = (const float*)d_in[6];
    const float* w4  = (const float*)d_in[7];
    const float* b4  = (const float*)d_in[8];
    const float* w32 = (const float*)d_in[9];
    const float* b32 = (const float*)d_in[10];
    const float* wf  = (const float*)d_in[11];
    const float* bf  = (const float*)d_in[12];
    const float* mw0 = (const float*)d_in[13];
    const float* mb0 = (const float*)d_in[14];
    const float* mw1 = (const float*)d_in[15];
    const float* mb1 = (const float*)d_in[16];
    const float* mw2 = (const float*)d_in[17];
    const float* mb2 = (const float*)d_in[18];

    float* ws   = (float*)d_ws;
    float* a4s  = ws;                   // 2*96*96*32   = 589824
    float* a32s = a4s  + 589824;        // 2*24*24*32   = 36864
    float* xcat = a32s + 36864;         // 2*192*192*96 = 7077888
    float* aspp = xcat + 7077888;       // 7077888
    float* w1T  = aspp + 7077888;       // 64*64 = 4096
    float* out  = (float*)d_out;

    prep_weights<<<16, 256, 0, stream>>>(mw1, w1T);
    conv1x1_relu<96><<<2304, 256, 0, stream>>>(feats4, w4, b4, a4s, 2 * 96 * 96);
    conv1x1_relu<160><<<144, 256, 0, stream>>>(feats32, w32, b32, a32s, 2 * 24 * 24);
    conv1x1_relu_into96<<<9216, 256, 0, stream>>>(feats2, w2, b2, xcat, 2 * HA * HA);
    upsample_into96<<<9216, 256, 0, stream>>>(a4s, xcat, 96, 0.5f, 32);
    upsample_into96<<<9216, 256, 0, stream>>>(a32s, xcat, 24, 0.125f, 64);
    conv3x3_relu<<<dim3(12, 12, 2), dim3(16, 16), 0, stream>>>(xcat, wf, bf, aspp);
    decoder_mlp<<<1152, 256, 0, stream>>>(aspp, coords, cells, mw0, mb0,
                                          w1T, mb1, mw2, mb2, out);
}

// Round 3
// 769.617 us; speedup vs baseline: 3.6374x; 1.6084x over previous
//
#include <hip/hip_runtime.h>
#include <math.h>

// ---------------------------------------------------------------------------
// Decoder_82764019794508: LIIF-style decoder, fp32.
// R3: occupancy + AGPR-shuffle fixes.
//   decoder_mlp: 1 corner per lane (4 lanes/query), __launch_bounds__(256,4)
//                keeps h[64] in arch VGPRs; quad shfl_xor combine.
//   conv3x3   : 24 output channels per block (blockIdx.z splits 4 groups),
//                acc[24], ~24 waves/CU.
// ---------------------------------------------------------------------------

#define HQ 384
#define HA 192

// ---- K0: transpose mw1 (64x64) -> w1T so layer1 rows are contiguous -------
__global__ void prep_weights(const float* __restrict__ mw1,
                             float* __restrict__ w1T) {
    int t = blockIdx.x * blockDim.x + threadIdx.x;
    if (t < 64 * 64) {
        int j = t >> 6, i = t & 63;
        w1T[t] = mw1[i * 64 + j];  // w1T[j][i] = mw1[i][j]
    }
}

// ---- K1/K2: 1x1 conv + ReLU, CIN -> 32, contiguous output -----------------
template <int CIN>
__global__ void conv1x1_relu(const float* __restrict__ x,
                             const float* __restrict__ w,
                             const float* __restrict__ b,
                             float* __restrict__ y, int npix) {
    int t = blockIdx.x * blockDim.x + threadIdx.x;
    int p = t >> 5, c = t & 31;
    if (p >= npix) return;
    const float* xr = x + (size_t)p * CIN;
    float acc = b[c];
#pragma unroll
    for (int i = 0; i < CIN; ++i) acc = fmaf(xr[i], w[i * 32 + c], acc);
    y[(size_t)p * 32 + c] = fmaxf(acc, 0.f);
}

// ---- K3a: 1x1 conv (64->32) + ReLU writing into 96-ch concat buffer -------
__global__ void conv1x1_relu_into96(const float* __restrict__ x,
                                    const float* __restrict__ w,
                                    const float* __restrict__ b,
                                    float* __restrict__ y, int npix) {
    int t = blockIdx.x * blockDim.x + threadIdx.x;
    int p = t >> 5, c = t & 31;
    if (p >= npix) return;
    const float* xr = x + (size_t)p * 64;
    float acc = b[c];
#pragma unroll
    for (int i = 0; i < 64; ++i) acc = fmaf(xr[i], w[i * 32 + c], acc);
    y[(size_t)p * 96 + c] = fmaxf(acc, 0.f);
}

// ---- K3b+K3c merged: bilinear upsample both sources into xcat -------------
// first 9216 blocks: a4s (S=96, inv=0.5, coff=32); rest: a32s (S=24, .125, 64)
__global__ void upsample_into96_2(const float* __restrict__ srcA,
                                  const float* __restrict__ srcB,
                                  float* __restrict__ dst) {
    int blk = blockIdx.x;
    const float* src;
    int S, coff;
    float inv;
    if (blk < 9216) { src = srcA; S = 96; inv = 0.5f;   coff = 32; }
    else            { src = srcB; S = 24; inv = 0.125f; coff = 64; blk -= 9216; }

    int t = blk * blockDim.x + threadIdx.x;
    int c = t & 31;
    int r = t >> 5;
    int x = r % HA; r /= HA;
    int y = r % HA; int b = r / HA;

    float u = ((float)y + 0.5f) * inv - 0.5f;
    float v = ((float)x + 0.5f) * inv - 0.5f;
    float fu = floorf(u), fv = floorf(v);
    float wu = u - fu, wv = v - fv;
    int y0 = (int)fu, x0 = (int)fv;
    int y1 = min(y0 + 1, S - 1);
    int x1 = min(x0 + 1, S - 1);
    y0 = max(y0, 0);
    x0 = max(x0, 0);

    const float* sb = src + (size_t)b * S * S * 32 + c;
    float v00 = sb[(y0 * S + x0) * 32];
    float v01 = sb[(y0 * S + x1) * 32];
    float v10 = sb[(y1 * S + x0) * 32];
    float v11 = sb[(y1 * S + x1) * 32];
    float t0 = v00 * (1.f - wu) + v10 * wu;
    float t1 = v01 * (1.f - wu) + v11 * wu;
    float o  = t0 * (1.f - wv) + t1 * wv;
    dst[(((size_t)b * HA + y) * HA + x) * 96 + coff + c] = o;
}

// ---- K4: 3x3 conv 96->96 + bias + ReLU, zero ("SAME") padding -------------
// block = 16x16 pixels x 24 output channels (blockIdx.z: b*4 + channel group)
__launch_bounds__(256, 6)
__global__ void conv3x3_relu(const float* __restrict__ x,
                             const float* __restrict__ w,
                             const float* __restrict__ bias,
                             float* __restrict__ y) {
    __shared__ float lds[16 * 18 * 18];  // 20.7 KB
    const int tx = threadIdx.x, ty = threadIdx.y;
    const int bx = blockIdx.x * 16, by = blockIdx.y * 16;
    const int cg = blockIdx.z & 3;
    const int b  = blockIdx.z >> 2;
    const int co0 = cg * 24;
    const int tid = ty * 16 + tx;

    float acc[24];
#pragma unroll
    for (int co = 0; co < 24; ++co) acc[co] = 0.f;

    for (int chunk = 0; chunk < 6; ++chunk) {
        __syncthreads();
        for (int idx = tid; idx < 16 * 18 * 18; idx += 256) {
            int i = idx & 15;
            int pos = idx >> 4;
            int lx = pos % 18;
            int ly = pos / 18;
            int gy = by + ly - 1, gx = bx + lx - 1;
            float v = 0.f;
            if (gy >= 0 && gy < HA && gx >= 0 && gx < HA)
                v = x[(((size_t)b * HA + gy) * HA + gx) * 96 + chunk * 16 + i];
            lds[i * 324 + ly * 18 + lx] = v;
        }
        __syncthreads();
#pragma unroll
        for (int ky = 0; ky < 3; ++ky)
#pragma unroll
            for (int kx = 0; kx < 3; ++kx)
#pragma unroll 4
                for (int i = 0; i < 16; ++i) {
                    float v = lds[i * 324 + (ty + ky) * 18 + (tx + kx)];
                    const float* wr =
                        w + ((ky * 3 + kx) * 96 + chunk * 16 + i) * 96 + co0;
#pragma unroll
                    for (int co = 0; co < 24; ++co)
                        acc[co] = fmaf(v, wr[co], acc[co]);
                }
    }

    float* yp = y + (((size_t)b * HA + by + ty) * HA + bx + tx) * 96 + co0;
#pragma unroll
    for (int q = 0; q < 6; ++q) {
        float4 o;
        o.x = fmaxf(acc[q * 4 + 0] + bias[co0 + q * 4 + 0], 0.f);
        o.y = fmaxf(acc[q * 4 + 1] + bias[co0 + q * 4 + 1], 0.f);
        o.z = fmaxf(acc[q * 4 + 2] + bias[co0 + q * 4 + 2], 0.f);
        o.w = fmaxf(acc[q * 4 + 3] + bias[co0 + q * 4 + 3], 0.f);
        ((float4*)yp)[q] = o;
    }
}

// ---- K5: 4-corner gather + MLP ensemble, ONE CORNER PER LANE --------------
// t = q*4 + k (query q, corner k). Quad combine via shfl_xor(3/1/2).
// __launch_bounds__(256,4): 128-VGPR cap keeps h[64] in arch VGPRs.
__launch_bounds__(256, 4)
__global__ void decoder_mlp(const float* __restrict__ aspp,
                            const float* __restrict__ coords,
                            const float* __restrict__ cells,
                            const float* __restrict__ mw0,
                            const float* __restrict__ mb0,
                            const float* __restrict__ w1T,
                            const float* __restrict__ mb1,
                            const float* __restrict__ mw2,
                            const float* __restrict__ mb2,
                            float* __restrict__ out) {
    const int t = blockIdx.x * 256 + threadIdx.x;  // exact: 4*2*384*384
    const int q = t >> 2;
    const int k = t & 3;
    const int b = q / (HQ * HQ);

    const float cy = coords[(size_t)q * 2 + 0];
    const float cx = coords[(size_t)q * 2 + 1];
    const float rcy = cells[(size_t)q * 2 + 0] * (float)HA;
    const float rcx = cells[(size_t)q * 2 + 1] * (float)HA;

    const float LO = -1.0f + 1e-7f, HI = 1.0f - 1e-7f;
    const float RXY = 1.0f / (float)HA;

    const float vy = (k < 2) ? -1.f : 1.f;
    const float vx = (k & 1) ? 1.f : -1.f;

    float c0 = fminf(fmaxf((cy + vy * RXY) + 1e-7f, LO), HI);
    float c1 = fminf(fmaxf((cx + vx * RXY) + 1e-7f, LO), HI);
    int iy = (int)rintf(((c0 + 1.f) * (float)HA) * 0.5f - 0.5f);
    int ix = (int)rintf(((c1 + 1.f) * (float)HA) * 0.5f - 0.5f);
    iy = min(max(iy, 0), HA - 1);
    ix = min(max(ix, 0), HA - 1);

    const float cs0 = (((float)iy + 0.5f) / (float)HA) * 2.f - 1.f;
    const float cs1 = (((float)ix + 0.5f) / (float)HA) * 2.f - 1.f;
    const float r0 = (cy - cs0) * (float)HA;
    const float r1 = (cx - cs1) * (float)HA;
    const float area = fabsf(r0 * r1) + 1e-7f;

    const float4* fp4 =
        (const float4*)(aspp + (((size_t)b * HA + iy) * HA + ix) * 96);

    float h[64];
#pragma unroll
    for (int j = 0; j < 64; ++j) h[j] = mb0[j];

    auto l0row = [&](float v, int row) {
        const float* wr = mw0 + row * 64;
#pragma unroll
        for (int j = 0; j < 64; ++j) h[j] = fmaf(v, wr[j], h[j]);
    };

    // ---- layer0: stream 24 float4 feature chunks (double-buffered) ----
    float4 u0 = fp4[0];
    float4 u1 = fp4[1];
#pragma unroll 1
    for (int qq = 0; qq < 24; qq += 2) {
        float4 ca = u0;
        if (qq + 2 < 24) u0 = fp4[qq + 2];
        l0row(ca.x, 4 * qq + 0);
        l0row(ca.y, 4 * qq + 1);
        l0row(ca.z, 4 * qq + 2);
        l0row(ca.w, 4 * qq + 3);
        float4 cb = u1;
        if (qq + 3 < 24) u1 = fp4[qq + 3];
        l0row(cb.x, 4 * qq + 4);
        l0row(cb.y, 4 * qq + 5);
        l0row(cb.z, 4 * qq + 6);
        l0row(cb.w, 4 * qq + 7);
    }
    l0row(r0, 96);
    l0row(r1, 97);
    l0row(cy, 98);
    l0row(cx, 99);
    l0row(rcy, 100);
    l0row(rcx, 101);

#pragma unroll
    for (int j = 0; j < 64; ++j) h[j] = fmaxf(h[j], 0.f);

    // ---- layer1 + layer2 fused ----
    float pred = mb2[0];
#pragma unroll 1
    for (int j = 0; j < 64; ++j) {
        const float* wr = w1T + j * 64;
        float acc = mb1[j];
#pragma unroll
        for (int i = 0; i < 64; ++i) acc = fmaf(h[i], wr[i], acc);
        pred = fmaf(fmaxf(acc, 0.f), mw2[j], pred);
    }

    // pred_k pairs with area_{3-k}: lane xor 3 inside the quad
    float apair = __shfl_xor(area, 3, 64);
    float num = pred * apair;
    num += __shfl_xor(num, 1, 64);
    num += __shfl_xor(num, 2, 64);
    float den = area;
    den += __shfl_xor(den, 1, 64);
    den += __shfl_xor(den, 2, 64);

    if (k == 0) out[q] = num / den;
}

// ---------------------------------------------------------------------------
extern "C" void kernel_launch(void* const* d_in, const int* in_sizes, int n_in,
                              void* d_out, int out_size, void* d_ws, size_t ws_size,
                              hipStream_t stream) {
    (void)in_sizes; (void)n_in; (void)out_size; (void)ws_size;
    const float* feats2  = (const float*)d_in[0];
    const float* feats4  = (const float*)d_in[1];
    const float* feats32 = (const float*)d_in[2];
    const float* coords  = (const float*)d_in[3];
    const float* cells   = (const float*)d_in[4];
    const float* w2  = (const float*)d_in[5];
    const float* b2  = (const float*)d_in[6];
    const float* w4  = (const float*)d_in[7];
    const float* b4  = (const float*)d_in[8];
    const float* w32 = (const float*)d_in[9];
    const float* b32 = (const float*)d_in[10];
    const float* wf  = (const float*)d_in[11];
    const float* bf  = (const float*)d_in[12];
    const float* mw0 = (const float*)d_in[13];
    const float* mb0 = (const float*)d_in[14];
    const float* mw1 = (const float*)d_in[15];
    const float* mb1 = (const float*)d_in[16];
    const float* mw2 = (const float*)d_in[17];
    const float* mb2 = (const float*)d_in[18];

    float* ws   = (float*)d_ws;
    float* a4s  = ws;                   // 2*96*96*32   = 589824
    float* a32s = a4s  + 589824;        // 2*24*24*32   = 36864
    float* xcat = a32s + 36864;         // 2*192*192*96 = 7077888
    float* aspp = xcat + 7077888;       // 7077888
    float* w1T  = aspp + 7077888;       // 64*64 = 4096
    float* out  = (float*)d_out;

    prep_weights<<<16, 256, 0, stream>>>(mw1, w1T);
    conv1x1_relu<96><<<2304, 256, 0, stream>>>(feats4, w4, b4, a4s, 2 * 96 * 96);
    conv1x1_relu<160><<<144, 256, 0, stream>>>(feats32, w32, b32, a32s, 2 * 24 * 24);
    conv1x1_relu_into96<<<9216, 256, 0, stream>>>(feats2, w2, b2, xcat, 2 * HA * HA);
    upsample_into96_2<<<18432, 256, 0, stream>>>(a4s, a32s, xcat);
    conv3x3_relu<<<dim3(12, 12, 8), dim3(16, 16), 0, stream>>>(xcat, wf, bf, aspp);
    decoder_mlp<<<4608, 256, 0, stream>>>(aspp, coords, cells, mw0, mb0,
                                          w1T, mb1, mw2, mb2, out);
}

// Round 5
// 489.333 us; speedup vs baseline: 5.7209x; 1.5728x over previous
//
#include <hip/hip_runtime.h>
#include <math.h>

// ---------------------------------------------------------------------------
// Decoder_82764019794508: LIIF-style decoder.
// R5 (= R4 resubmit after infra failure): decoder_mlp -> fp16 MFMA
// (16x16x32_f16, fp32 accum).
//   - 128 (query,corner) rows per 256-thread block; coalesced 16-lane/row
//     gather into XOR-swizzled LDS A-tile (K 102->128 zero-padded)
//   - weights pre-packed into per-lane MFMA fragments (prep_frags)
//   - layer2 + area combine in fp32 (quad shfl reduction), same numerics
//     as the passing R3 path for indices/areas.
// ---------------------------------------------------------------------------

#define HQ 384
#define HA 192

typedef _Float16 half8  __attribute__((ext_vector_type(8)));
typedef _Float16 half4v __attribute__((ext_vector_type(4)));
typedef float    float4v __attribute__((ext_vector_type(4)));

// ---- K0: pack MLP weights into per-lane MFMA B-fragments ------------------
// frag f<16: layer0 (kc=f>>2, nt=f&3), K=128 zero-padded past 102.
// frag f>=16: layer1 (g=f-16, kc=g>>2 in {0,1}, nt=g&3).
// B-operand lane map: n = lane&15, k = (lane>>4)*8 + j.
__global__ void prep_frags(const float* __restrict__ mw0,
                           const float* __restrict__ mw1,
                           _Float16* __restrict__ fragTab) {
    int t = blockIdx.x * 256 + threadIdx.x;
    if (t >= 24 * 64) return;
    int f = t >> 6, L = t & 63;
    int n_ = L & 15, qd = L >> 4;
    _Float16 vals[8];
    if (f < 16) {
        int kc = f >> 2, nt = f & 3;
#pragma unroll
        for (int j = 0; j < 8; ++j) {
            int kk = kc * 32 + qd * 8 + j;
            vals[j] = (_Float16)((kk < 102) ? mw0[kk * 64 + nt * 16 + n_] : 0.f);
        }
    } else {
        int g = f - 16;
        int kc = g >> 2, nt = g & 3;
#pragma unroll
        for (int j = 0; j < 8; ++j) {
            int kk = kc * 32 + qd * 8 + j;
            vals[j] = (_Float16)mw1[kk * 64 + nt * 16 + n_];
        }
    }
#pragma unroll
    for (int j = 0; j < 8; ++j) fragTab[t * 8 + j] = vals[j];
}

// ---- K1/K2: 1x1 conv + ReLU, CIN -> 32, contiguous output -----------------
template <int CIN>
__global__ void conv1x1_relu(const float* __restrict__ x,
                             const float* __restrict__ w,
                             const float* __restrict__ b,
                             float* __restrict__ y, int npix) {
    int t = blockIdx.x * blockDim.x + threadIdx.x;
    int p = t >> 5, c = t & 31;
    if (p >= npix) return;
    const float* xr = x + (size_t)p * CIN;
    float acc = b[c];
#pragma unroll
    for (int i = 0; i < CIN; ++i) acc = fmaf(xr[i], w[i * 32 + c], acc);
    y[(size_t)p * 32 + c] = fmaxf(acc, 0.f);
}

// ---- K3a: 1x1 conv (64->32) + ReLU writing into 96-ch concat buffer -------
__global__ void conv1x1_relu_into96(const float* __restrict__ x,
                                    const float* __restrict__ w,
                                    const float* __restrict__ b,
                                    float* __restrict__ y, int npix) {
    int t = blockIdx.x * blockDim.x + threadIdx.x;
    int p = t >> 5, c = t & 31;
    if (p >= npix) return;
    const float* xr = x + (size_t)p * 64;
    float acc = b[c];
#pragma unroll
    for (int i = 0; i < 64; ++i) acc = fmaf(xr[i], w[i * 32 + c], acc);
    y[(size_t)p * 96 + c] = fmaxf(acc, 0.f);
}

// ---- K3b+K3c merged: bilinear upsample both sources into xcat -------------
__global__ void upsample_into96_2(const float* __restrict__ srcA,
                                  const float* __restrict__ srcB,
                                  float* __restrict__ dst) {
    int blk = blockIdx.x;
    const float* src;
    int S, coff;
    float inv;
    if (blk < 9216) { src = srcA; S = 96; inv = 0.5f;   coff = 32; }
    else            { src = srcB; S = 24; inv = 0.125f; coff = 64; blk -= 9216; }

    int t = blk * blockDim.x + threadIdx.x;
    int c = t & 31;
    int r = t >> 5;
    int x = r % HA; r /= HA;
    int y = r % HA; int b = r / HA;

    float u = ((float)y + 0.5f) * inv - 0.5f;
    float v = ((float)x + 0.5f) * inv - 0.5f;
    float fu = floorf(u), fv = floorf(v);
    float wu = u - fu, wv = v - fv;
    int y0 = (int)fu, x0 = (int)fv;
    int y1 = min(y0 + 1, S - 1);
    int x1 = min(x0 + 1, S - 1);
    y0 = max(y0, 0);
    x0 = max(x0, 0);

    const float* sb = src + (size_t)b * S * S * 32 + c;
    float v00 = sb[(y0 * S + x0) * 32];
    float v01 = sb[(y0 * S + x1) * 32];
    float v10 = sb[(y1 * S + x0) * 32];
    float v11 = sb[(y1 * S + x1) * 32];
    float t0 = v00 * (1.f - wu) + v10 * wu;
    float t1 = v01 * (1.f - wu) + v11 * wu;
    float o  = t0 * (1.f - wv) + t1 * wv;
    dst[(((size_t)b * HA + y) * HA + x) * 96 + coff + c] = o;
}

// ---- K4: 3x3 conv 96->96 + bias + ReLU, zero ("SAME") padding -------------
__launch_bounds__(256, 6)
__global__ void conv3x3_relu(const float* __restrict__ x,
                             const float* __restrict__ w,
                             const float* __restrict__ bias,
                             float* __restrict__ y) {
    __shared__ float lds[16 * 18 * 18];  // 20.7 KB
    const int tx = threadIdx.x, ty = threadIdx.y;
    const int bx = blockIdx.x * 16, by = blockIdx.y * 16;
    const int cg = blockIdx.z & 3;
    const int b  = blockIdx.z >> 2;
    const int co0 = cg * 24;
    const int tid = ty * 16 + tx;

    float acc[24];
#pragma unroll
    for (int co = 0; co < 24; ++co) acc[co] = 0.f;

    for (int chunk = 0; chunk < 6; ++chunk) {
        __syncthreads();
        for (int idx = tid; idx < 16 * 18 * 18; idx += 256) {
            int i = idx & 15;
            int pos = idx >> 4;
            int lx = pos % 18;
            int ly = pos / 18;
            int gy = by + ly - 1, gx = bx + lx - 1;
            float v = 0.f;
            if (gy >= 0 && gy < HA && gx >= 0 && gx < HA)
                v = x[(((size_t)b * HA + gy) * HA + gx) * 96 + chunk * 16 + i];
            lds[i * 324 + ly * 18 + lx] = v;
        }
        __syncthreads();
#pragma unroll
        for (int ky = 0; ky < 3; ++ky)
#pragma unroll
            for (int kx = 0; kx < 3; ++kx)
#pragma unroll 4
                for (int i = 0; i < 16; ++i) {
                    float v = lds[i * 324 + (ty + ky) * 18 + (tx + kx)];
                    const float* wr =
                        w + ((ky * 3 + kx) * 96 + chunk * 16 + i) * 96 + co0;
#pragma unroll
                    for (int co = 0; co < 24; ++co)
                        acc[co] = fmaf(v, wr[co], acc[co]);
                }
    }

    float* yp = y + (((size_t)b * HA + by + ty) * HA + bx + tx) * 96 + co0;
#pragma unroll
    for (int q = 0; q < 6; ++q) {
        float4 o;
        o.x = fmaxf(acc[q * 4 + 0] + bias[co0 + q * 4 + 0], 0.f);
        o.y = fmaxf(acc[q * 4 + 1] + bias[co0 + q * 4 + 1], 0.f);
        o.z = fmaxf(acc[q * 4 + 2] + bias[co0 + q * 4 + 2], 0.f);
        o.w = fmaxf(acc[q * 4 + 3] + bias[co0 + q * 4 + 3], 0.f);
        ((float4*)yp)[q] = o;
    }
}

// ---- K5: 4-corner gather + MLP ensemble via fp16 MFMA ---------------------
// Block: 256 threads (4 waves) = 128 rows = 32 queries x 4 corners.
// LDS: A[128][128]h (xor-swizzled 16B units), H[128][64]h (xor-swizzled),
//      pix[128]i, area[128]f, pred[128]f  => 50,688 B => 3 blocks/CU.
__launch_bounds__(256, 3)
__global__ void decoder_mlp_mfma(const float* __restrict__ aspp,
                                 const float* __restrict__ coords,
                                 const float* __restrict__ cells,
                                 const _Float16* __restrict__ fragTab,
                                 const float* __restrict__ mb0,
                                 const float* __restrict__ mb1,
                                 const float* __restrict__ mw2,
                                 const float* __restrict__ mb2,
                                 float* __restrict__ out) {
    __shared__ __align__(16) unsigned char smem[50688];
    _Float16* A   = (_Float16*)smem;              // 32768 B
    _Float16* Hb  = (_Float16*)(smem + 32768);    // 16384 B
    int*      pixL  = (int*)(smem + 49152);       // 512 B
    float*    areaL = (float*)(smem + 49664);     // 512 B
    float*    predL = (float*)(smem + 50176);     // 512 B

    const int tid  = threadIdx.x;
    const int lane = tid & 63;
    const int wv   = tid >> 6;
    const int n_   = lane & 15;
    const int qd   = lane >> 4;

    // ---------- phase 0: indices, areas, extras (threads 0..127) ----------
    if (tid < 128) {
        const int lq = tid >> 2, k = tid & 3;
        const int q  = blockIdx.x * 32 + lq;
        const int b  = q / (HQ * HQ);
        const float cy = coords[(size_t)q * 2 + 0];
        const float cx = coords[(size_t)q * 2 + 1];
        const float rcy = cells[(size_t)q * 2 + 0] * (float)HA;
        const float rcx = cells[(size_t)q * 2 + 1] * (float)HA;

        const float LO = -1.0f + 1e-7f, HI = 1.0f - 1e-7f;
        const float RXY = 1.0f / (float)HA;
        const float vy = (k < 2) ? -1.f : 1.f;
        const float vx = (k & 1) ? 1.f : -1.f;

        float c0 = fminf(fmaxf((cy + vy * RXY) + 1e-7f, LO), HI);
        float c1 = fminf(fmaxf((cx + vx * RXY) + 1e-7f, LO), HI);
        int iy = (int)rintf(((c0 + 1.f) * (float)HA) * 0.5f - 0.5f);
        int ix = (int)rintf(((c1 + 1.f) * (float)HA) * 0.5f - 0.5f);
        iy = min(max(iy, 0), HA - 1);
        ix = min(max(ix, 0), HA - 1);

        const float cs0 = (((float)iy + 0.5f) / (float)HA) * 2.f - 1.f;
        const float cs1 = (((float)ix + 0.5f) / (float)HA) * 2.f - 1.f;
        const float r0 = (cy - cs0) * (float)HA;
        const float r1 = (cx - cs1) * (float)HA;

        pixL[tid]  = ((b * HA + iy) * HA + ix) * 96;
        areaL[tid] = fabsf(r0 * r1) + 1e-7f;

        // extras into A row tid, units 12..15 (halfs 96..127), swizzled
        const int row = tid;
        half8 e0;
        e0[0] = (_Float16)r0;  e0[1] = (_Float16)r1;
        e0[2] = (_Float16)cy;  e0[3] = (_Float16)cx;
        e0[4] = (_Float16)rcy; e0[5] = (_Float16)rcx;
        e0[6] = (_Float16)0.f; e0[7] = (_Float16)0.f;
        half8 z = {(_Float16)0.f, (_Float16)0.f, (_Float16)0.f, (_Float16)0.f,
                   (_Float16)0.f, (_Float16)0.f, (_Float16)0.f, (_Float16)0.f};
        *(half8*)&A[row * 128 + ((12 ^ (row & 15)) * 8)] = e0;
        *(half8*)&A[row * 128 + ((13 ^ (row & 15)) * 8)] = z;
        *(half8*)&A[row * 128 + ((14 ^ (row & 15)) * 8)] = z;
        *(half8*)&A[row * 128 + ((15 ^ (row & 15)) * 8)] = z;
    }

    // ---------- resident layer0 weight fragments + biases ----------
    half8 B0[16];
#pragma unroll
    for (int i = 0; i < 16; ++i)
        B0[i] = *(const half8*)(fragTab + ((size_t)i * 64 + lane) * 8);
    float mb0v[4], mb1v[4], w2v[4];
#pragma unroll
    for (int nt = 0; nt < 4; ++nt) {
        mb0v[nt] = mb0[nt * 16 + n_];
        mb1v[nt] = mb1[nt * 16 + n_];
        w2v[nt]  = mw2[nt * 16 + n_];
    }
    const float mb2s = mb2[0];

    __syncthreads();

    // ---------- coalesced gather: 16 lanes per row ----------
    {
        const int grp = tid >> 4;   // 0..15
        const int l   = tid & 15;
#pragma unroll 1
        for (int it = 0; it < 8; ++it) {
            const int row  = it * 16 + grp;
            const int base = pixL[row];
            float4v v = *(const float4v*)(aspp + base + l * 4);
            half4v h;
            h[0] = (_Float16)v[0]; h[1] = (_Float16)v[1];
            h[2] = (_Float16)v[2]; h[3] = (_Float16)v[3];
            *(half4v*)&A[row * 128 + (((l >> 1) ^ (row & 15)) * 8) + (l & 1) * 4] = h;
            if (l < 8) {
                const int qt = 16 + l;
                float4v v2 = *(const float4v*)(aspp + base + qt * 4);
                half4v h2;
                h2[0] = (_Float16)v2[0]; h2[1] = (_Float16)v2[1];
                h2[2] = (_Float16)v2[2]; h2[3] = (_Float16)v2[3];
                *(half4v*)&A[row * 128 + (((qt >> 1) ^ (row & 15)) * 8) + (qt & 1) * 4] = h2;
            }
        }
    }
    __syncthreads();

    // ---------- MFMA: 2 M-tiles of 16 rows per wave ----------
#pragma unroll 1
    for (int mt = 0; mt < 2; ++mt) {
        const int m0  = wv * 32 + mt * 16;
        const int row = m0 + n_;

        // layer0: C = A(16x128) * W0(128x64)
        float4v acc[4];
#pragma unroll
        for (int nt = 0; nt < 4; ++nt) {
            float4v t = {mb0v[nt], mb0v[nt], mb0v[nt], mb0v[nt]};
            acc[nt] = t;
        }
#pragma unroll
        for (int kc = 0; kc < 4; ++kc) {
            half8 a = *(const half8*)&A[row * 128 + (((kc * 4 + qd) ^ (row & 15)) * 8)];
#pragma unroll
            for (int nt = 0; nt < 4; ++nt)
                acc[nt] = __builtin_amdgcn_mfma_f32_16x16x32_f16(a, B0[kc * 4 + nt],
                                                                 acc[nt], 0, 0, 0);
        }
        // relu -> H (fp16, swizzled)
#pragma unroll
        for (int nt = 0; nt < 4; ++nt)
#pragma unroll
            for (int reg = 0; reg < 4; ++reg) {
                const int hr = m0 + qd * 4 + reg;
                const int n  = nt * 16 + n_;
                Hb[hr * 64 + (((n >> 3) ^ (hr & 7)) * 8) + (n & 7)] =
                    (_Float16)fmaxf(acc[nt][reg], 0.f);
            }
        __builtin_amdgcn_s_waitcnt(0);  // drain LDS writes (within-wave dep)

        // layer1: C1 = H(16x64) * W1(64x64)   (fragments reloaded per M-tile)
        float4v acc1[4];
#pragma unroll
        for (int nt = 0; nt < 4; ++nt) {
            float4v t = {mb1v[nt], mb1v[nt], mb1v[nt], mb1v[nt]};
            acc1[nt] = t;
        }
#pragma unroll
        for (int kc = 0; kc < 2; ++kc) {
            half8 a1 = *(const half8*)&Hb[row * 64 + (((kc * 4 + qd) ^ (row & 7)) * 8)];
#pragma unroll
            for (int nt = 0; nt < 4; ++nt) {
                half8 b1 = *(const half8*)(fragTab +
                            ((size_t)(16 + kc * 4 + nt) * 64 + lane) * 8);
                acc1[nt] = __builtin_amdgcn_mfma_f32_16x16x32_f16(a1, b1,
                                                                  acc1[nt], 0, 0, 0);
            }
        }

        // layer2 (fp32): pred_row = mb2 + sum_n relu(h1[n]) * mw2[n]
        float p[4];
#pragma unroll
        for (int reg = 0; reg < 4; ++reg) {
            float s = 0.f;
#pragma unroll
            for (int nt = 0; nt < 4; ++nt)
                s = fmaf(fmaxf(acc1[nt][reg], 0.f), w2v[nt], s);
            s += __shfl_xor(s, 1, 64);
            s += __shfl_xor(s, 2, 64);
            s += __shfl_xor(s, 4, 64);
            s += __shfl_xor(s, 8, 64);
            p[reg] = s;
        }
        if (n_ == 0) {
            float4v pv = {p[0] + mb2s, p[1] + mb2s, p[2] + mb2s, p[3] + mb2s};
            *(float4v*)&predL[m0 + qd * 4] = pv;
        }
    }
    __syncthreads();

    // ---------- combine: pred_k pairs with area_{3-k} ----------
    if (tid < 32) {
        float4v pr = *(const float4v*)&predL[tid * 4];
        float4v ar = *(const float4v*)&areaL[tid * 4];
        float num = pr[0] * ar[3] + pr[1] * ar[2] + pr[2] * ar[1] + pr[3] * ar[0];
        float den = ar[0] + ar[1] + ar[2] + ar[3];
        out[blockIdx.x * 32 + tid] = num / den;
    }
}

// ---------------------------------------------------------------------------
extern "C" void kernel_launch(void* const* d_in, const int* in_sizes, int n_in,
                              void* d_out, int out_size, void* d_ws, size_t ws_size,
                              hipStream_t stream) {
    (void)in_sizes; (void)n_in; (void)out_size; (void)ws_size;
    const float* feats2  = (const float*)d_in[0];
    const float* feats4  = (const float*)d_in[1];
    const float* feats32 = (const float*)d_in[2];
    const float* coords  = (const float*)d_in[3];
    const float* cells   = (const float*)d_in[4];
    const float* w2  = (const float*)d_in[5];
    const float* b2  = (const float*)d_in[6];
    const float* w4  = (const float*)d_in[7];
    const float* b4  = (const float*)d_in[8];
    const float* w32 = (const float*)d_in[9];
    const float* b32 = (const float*)d_in[10];
    const float* wf  = (const float*)d_in[11];
    const float* bf  = (const float*)d_in[12];
    const float* mw0 = (const float*)d_in[13];
    const float* mb0 = (const float*)d_in[14];
    const float* mw1 = (const float*)d_in[15];
    const float* mb1 = (const float*)d_in[16];
    const float* mw2 = (const float*)d_in[17];
    const float* mb2 = (const float*)d_in[18];

    float* ws   = (float*)d_ws;
    float* a4s  = ws;                   // 2*96*96*32   = 589824
    float* a32s = a4s  + 589824;        // 2*24*24*32   = 36864
    float* xcat = a32s + 36864;         // 2*192*192*96 = 7077888
    float* aspp = xcat + 7077888;       // 7077888
    _Float16* fragTab = (_Float16*)(aspp + 7077888);  // 24*64*8 halfs = 24 KB
    float* out  = (float*)d_out;

    prep_frags<<<6, 256, 0, stream>>>(mw0, mw1, fragTab);
    conv1x1_relu<96><<<2304, 256, 0, stream>>>(feats4, w4, b4, a4s, 2 * 96 * 96);
    conv1x1_relu<160><<<144, 256, 0, stream>>>(feats32, w32, b32, a32s, 2 * 24 * 24);
    conv1x1_relu_into96<<<9216, 256, 0, stream>>>(feats2, w2, b2, xcat, 2 * HA * HA);
    upsample_into96_2<<<18432, 256, 0, stream>>>(a4s, a32s, xcat);
    conv3x3_relu<<<dim3(12, 12, 8), dim3(16, 16), 0, stream>>>(xcat, wf, bf, aspp);
    decoder_mlp_mfma<<<9216, 256, 0, stream>>>(aspp, coords, cells, fragTab,
                                               mb0, mb1, mw2, mb2, out);
}

// Round 6
// 351.191 us; speedup vs baseline: 7.9712x; 1.3934x over previous
//
#include <hip/hip_runtime.h>
#include <math.h>

// ---------------------------------------------------------------------------
// Decoder_82764019794508: LIIF-style decoder.
// R6: conv3x3 -> fp16 MFMA (16x16x32_f16, fp32 accum), same recipe as the
// R5 decoder (which passed with no absmax change).
//   - block = 16x8 pixel tile, 4 waves; wave = 4 y-rows x 3 n-tiles
//   - 18x10x96 halo staged once to LDS in fp16 (pixel stride 104 halfs)
//   - wf pre-packed to per-lane B-fragments (prep_fragsW), streamed from L2
//   - epilogue bias+ReLU fp32, aspp stays fp32 (decoder unchanged from R5)
// ---------------------------------------------------------------------------

#define HQ 384
#define HA 192

typedef _Float16 half8  __attribute__((ext_vector_type(8)));
typedef _Float16 half4v __attribute__((ext_vector_type(4)));
typedef float    float4v __attribute__((ext_vector_type(4)));

// ---- K0a: pack MLP weights into per-lane MFMA B-fragments -----------------
// frag f<16: layer0 (kc=f>>2, nt=f&3), K=128 zero-padded past 102.
// frag f>=16: layer1 (g=f-16, kc=g>>2 in {0,1}, nt=g&3).
// B-operand lane map: n = lane&15, k = (lane>>4)*8 + j.
__global__ void prep_frags(const float* __restrict__ mw0,
                           const float* __restrict__ mw1,
                           _Float16* __restrict__ fragTab) {
    int t = blockIdx.x * 256 + threadIdx.x;
    if (t >= 24 * 64) return;
    int f = t >> 6, L = t & 63;
    int n_ = L & 15, qd = L >> 4;
    _Float16 vals[8];
    if (f < 16) {
        int kc = f >> 2, nt = f & 3;
#pragma unroll
        for (int j = 0; j < 8; ++j) {
            int kk = kc * 32 + qd * 8 + j;
            vals[j] = (_Float16)((kk < 102) ? mw0[kk * 64 + nt * 16 + n_] : 0.f);
        }
    } else {
        int g = f - 16;
        int kc = g >> 2, nt = g & 3;
#pragma unroll
        for (int j = 0; j < 8; ++j) {
            int kk = kc * 32 + qd * 8 + j;
            vals[j] = (_Float16)mw1[kk * 64 + nt * 16 + n_];
        }
    }
#pragma unroll
    for (int j = 0; j < 8; ++j) fragTab[t * 8 + j] = vals[j];
}

// ---- K0b: pack conv3x3 weights into per-lane MFMA B-fragments -------------
// step s = (ky*3+kx)*3 + kc  (27 steps of K=32);  nt = 0..5 (96 out ch).
// fragTabW[((s*6 + nt)*64 + lane)*8 + j] = wf[((ky*3+kx)*96 + kc*32+qd*8+j)*96
//                                             + nt*16 + n_]
__global__ void prep_fragsW(const float* __restrict__ wf,
                            _Float16* __restrict__ fragTabW) {
    int t = blockIdx.x * 256 + threadIdx.x;
    if (t >= 27 * 6 * 64) return;
    int s   = t / 384;
    int rem = t - s * 384;
    int nt  = rem >> 6;
    int L   = rem & 63;
    int n_  = L & 15, qd = L >> 4;
    int tap = s / 3, kc = s - tap * 3;
#pragma unroll
    for (int j = 0; j < 8; ++j) {
        int kch = kc * 32 + qd * 8 + j;
        fragTabW[t * 8 + j] = (_Float16)wf[(tap * 96 + kch) * 96 + nt * 16 + n_];
    }
}

// ---- K1/K2: 1x1 conv + ReLU, CIN -> 32, contiguous output -----------------
template <int CIN>
__global__ void conv1x1_relu(const float* __restrict__ x,
                             const float* __restrict__ w,
                             const float* __restrict__ b,
                             float* __restrict__ y, int npix) {
    int t = blockIdx.x * blockDim.x + threadIdx.x;
    int p = t >> 5, c = t & 31;
    if (p >= npix) return;
    const float* xr = x + (size_t)p * CIN;
    float acc = b[c];
#pragma unroll
    for (int i = 0; i < CIN; ++i) acc = fmaf(xr[i], w[i * 32 + c], acc);
    y[(size_t)p * 32 + c] = fmaxf(acc, 0.f);
}

// ---- K3a: 1x1 conv (64->32) + ReLU writing into 96-ch concat buffer -------
__global__ void conv1x1_relu_into96(const float* __restrict__ x,
                                    const float* __restrict__ w,
                                    const float* __restrict__ b,
                                    float* __restrict__ y, int npix) {
    int t = blockIdx.x * blockDim.x + threadIdx.x;
    int p = t >> 5, c = t & 31;
    if (p >= npix) return;
    const float* xr = x + (size_t)p * 64;
    float acc = b[c];
#pragma unroll
    for (int i = 0; i < 64; ++i) acc = fmaf(xr[i], w[i * 32 + c], acc);
    y[(size_t)p * 96 + c] = fmaxf(acc, 0.f);
}

// ---- K3b+K3c merged: bilinear upsample both sources into xcat -------------
__global__ void upsample_into96_2(const float* __restrict__ srcA,
                                  const float* __restrict__ srcB,
                                  float* __restrict__ dst) {
    int blk = blockIdx.x;
    const float* src;
    int S, coff;
    float inv;
    if (blk < 9216) { src = srcA; S = 96; inv = 0.5f;   coff = 32; }
    else            { src = srcB; S = 24; inv = 0.125f; coff = 64; blk -= 9216; }

    int t = blk * blockDim.x + threadIdx.x;
    int c = t & 31;
    int r = t >> 5;
    int x = r % HA; r /= HA;
    int y = r % HA; int b = r / HA;

    float u = ((float)y + 0.5f) * inv - 0.5f;
    float v = ((float)x + 0.5f) * inv - 0.5f;
    float fu = floorf(u), fv = floorf(v);
    float wu = u - fu, wv = v - fv;
    int y0 = (int)fu, x0 = (int)fv;
    int y1 = min(y0 + 1, S - 1);
    int x1 = min(x0 + 1, S - 1);
    y0 = max(y0, 0);
    x0 = max(x0, 0);

    const float* sb = src + (size_t)b * S * S * 32 + c;
    float v00 = sb[(y0 * S + x0) * 32];
    float v01 = sb[(y0 * S + x1) * 32];
    float v10 = sb[(y1 * S + x0) * 32];
    float v11 = sb[(y1 * S + x1) * 32];
    float t0 = v00 * (1.f - wu) + v10 * wu;
    float t1 = v01 * (1.f - wu) + v11 * wu;
    float o  = t0 * (1.f - wv) + t1 * wv;
    dst[(((size_t)b * HA + y) * HA + x) * 96 + coff + c] = o;
}

// ---- K4: 3x3 conv 96->96 + bias + ReLU via fp16 MFMA ----------------------
// Tile: 16 (x) x 8 (y) pixels. 4 waves: wave = (yg = wv>>1)*4 y-rows x
// (nh = wv&1)*3 n-tiles. K = 9 taps x 96 ch = 27 steps of 32.
// LDS: halo 10(y) x 18(x) x 96ch fp16, pixel stride 104 halfs = 37,440 B.
__launch_bounds__(256, 4)
__global__ void conv3x3_mfma(const float* __restrict__ x,
                             const _Float16* __restrict__ fragTabW,
                             const float* __restrict__ bias,
                             float* __restrict__ y) {
    __shared__ _Float16 lds[10 * 18 * 104];  // 37,440 B
    const int tid = threadIdx.x;
    const int lane = tid & 63;
    const int wv   = tid >> 6;
    const int n_   = lane & 15;
    const int qd   = lane >> 4;
    const int nh   = wv & 1;        // n half: n-tiles nh*3..nh*3+2
    const int yg   = wv >> 1;       // y group: rows yg*4..yg*4+3
    const int bx0  = blockIdx.x * 16;
    const int by0  = blockIdx.y * 8;
    const int b    = blockIdx.z;

    // ---- stage halo (10 x 18 x 96) -> LDS fp16 ----
    // 4320 float4 elements: idx -> hy (/432), hx (/24), cc (float4 within ch)
    for (int idx = tid; idx < 4320; idx += 256) {
        int hy  = idx / 432;
        int rem = idx - hy * 432;
        int hx  = rem / 24;
        int cc  = rem - hx * 24;
        int gy = by0 + hy - 1, gx = bx0 + hx - 1;
        float4v v = {0.f, 0.f, 0.f, 0.f};
        if (gy >= 0 && gy < HA && gx >= 0 && gx < HA)
            v = *(const float4v*)(x + (((size_t)b * HA + gy) * HA + gx) * 96 + cc * 4);
        half4v h;
        h[0] = (_Float16)v[0]; h[1] = (_Float16)v[1];
        h[2] = (_Float16)v[2]; h[3] = (_Float16)v[3];
        *(half4v*)&lds[(hy * 18 + hx) * 104 + cc * 4] = h;
    }

    // bias for this wave's 3 n-tiles (col = n_ per C-layout)
    float bv[3];
#pragma unroll
    for (int j = 0; j < 3; ++j) bv[j] = bias[(nh * 3 + j) * 16 + n_];

    __syncthreads();

    float4v acc[4][3];
#pragma unroll
    for (int r = 0; r < 4; ++r)
#pragma unroll
        for (int j = 0; j < 3; ++j) {
            float4v z = {0.f, 0.f, 0.f, 0.f};
            acc[r][j] = z;
        }

    // ---- K loop: 9 taps x 3 k-chunks ----
#pragma unroll 1
    for (int ky = 0; ky < 3; ++ky)
#pragma unroll 1
        for (int kx = 0; kx < 3; ++kx) {
            const int tap = ky * 3 + kx;
#pragma unroll
            for (int kc = 0; kc < 3; ++kc) {
                const int s = tap * 3 + kc;
                // B fragments for this wave's 3 n-tiles
                half8 bf[3];
#pragma unroll
                for (int j = 0; j < 3; ++j)
                    bf[j] = *(const half8*)(fragTabW +
                            ((size_t)(s * 6 + nh * 3 + j) * 64 + lane) * 8);
                // A fragments for 4 y-rows; m = lane&15 = x, k = qd*8+j
#pragma unroll
                for (int r = 0; r < 4; ++r) {
                    const int yr = yg * 4 + r;
                    half8 a = *(const half8*)&lds[((yr + ky) * 18 + (n_ + kx)) * 104
                                                  + kc * 32 + qd * 8];
#pragma unroll
                    for (int j = 0; j < 3; ++j)
                        acc[r][j] = __builtin_amdgcn_mfma_f32_16x16x32_f16(
                            a, bf[j], acc[r][j], 0, 0, 0);
                }
            }
        }

    // ---- epilogue: bias + ReLU, store fp32 ----
    // C layout: col(n) = lane&15, row(m=x) = qd*4+reg
#pragma unroll
    for (int r = 0; r < 4; ++r) {
        const int gy = by0 + yg * 4 + r;
#pragma unroll
        for (int j = 0; j < 3; ++j) {
            const int ch = (nh * 3 + j) * 16 + n_;
#pragma unroll
            for (int reg = 0; reg < 4; ++reg) {
                const int gx = bx0 + qd * 4 + reg;
                y[(((size_t)b * HA + gy) * HA + gx) * 96 + ch] =
                    fmaxf(acc[r][j][reg] + bv[j], 0.f);
            }
        }
    }
}

// ---- K5: 4-corner gather + MLP ensemble via fp16 MFMA (unchanged R5) ------
__launch_bounds__(256, 3)
__global__ void decoder_mlp_mfma(const float* __restrict__ aspp,
                                 const float* __restrict__ coords,
                                 const float* __restrict__ cells,
                                 const _Float16* __restrict__ fragTab,
                                 const float* __restrict__ mb0,
                                 const float* __restrict__ mb1,
                                 const float* __restrict__ mw2,
                                 const float* __restrict__ mb2,
                                 float* __restrict__ out) {
    __shared__ __align__(16) unsigned char smem[50688];
    _Float16* A   = (_Float16*)smem;              // 32768 B
    _Float16* Hb  = (_Float16*)(smem + 32768);    // 16384 B
    int*      pixL  = (int*)(smem + 49152);       // 512 B
    float*    areaL = (float*)(smem + 49664);     // 512 B
    float*    predL = (float*)(smem + 50176);     // 512 B

    const int tid  = threadIdx.x;
    const int lane = tid & 63;
    const int wv   = tid >> 6;
    const int n_   = lane & 15;
    const int qd   = lane >> 4;

    if (tid < 128) {
        const int lq = tid >> 2, k = tid & 3;
        const int q  = blockIdx.x * 32 + lq;
        const int b  = q / (HQ * HQ);
        const float cy = coords[(size_t)q * 2 + 0];
        const float cx = coords[(size_t)q * 2 + 1];
        const float rcy = cells[(size_t)q * 2 + 0] * (float)HA;
        const float rcx = cells[(size_t)q * 2 + 1] * (float)HA;

        const float LO = -1.0f + 1e-7f, HI = 1.0f - 1e-7f;
        const float RXY = 1.0f / (float)HA;
        const float vy = (k < 2) ? -1.f : 1.f;
        const float vx = (k & 1) ? 1.f : -1.f;

        float c0 = fminf(fmaxf((cy + vy * RXY) + 1e-7f, LO), HI);
        float c1 = fminf(fmaxf((cx + vx * RXY) + 1e-7f, LO), HI);
        int iy = (int)rintf(((c0 + 1.f) * (float)HA) * 0.5f - 0.5f);
        int ix = (int)rintf(((c1 + 1.f) * (float)HA) * 0.5f - 0.5f);
        iy = min(max(iy, 0), HA - 1);
        ix = min(max(ix, 0), HA - 1);

        const float cs0 = (((float)iy + 0.5f) / (float)HA) * 2.f - 1.f;
        const float cs1 = (((float)ix + 0.5f) / (float)HA) * 2.f - 1.f;
        const float r0 = (cy - cs0) * (float)HA;
        const float r1 = (cx - cs1) * (float)HA;

        pixL[tid]  = ((b * HA + iy) * HA + ix) * 96;
        areaL[tid] = fabsf(r0 * r1) + 1e-7f;

        const int row = tid;
        half8 e0;
        e0[0] = (_Float16)r0;  e0[1] = (_Float16)r1;
        e0[2] = (_Float16)cy;  e0[3] = (_Float16)cx;
        e0[4] = (_Float16)rcy; e0[5] = (_Float16)rcx;
        e0[6] = (_Float16)0.f; e0[7] = (_Float16)0.f;
        half8 z = {(_Float16)0.f, (_Float16)0.f, (_Float16)0.f, (_Float16)0.f,
                   (_Float16)0.f, (_Float16)0.f, (_Float16)0.f, (_Float16)0.f};
        *(half8*)&A[row * 128 + ((12 ^ (row & 15)) * 8)] = e0;
        *(half8*)&A[row * 128 + ((13 ^ (row & 15)) * 8)] = z;
        *(half8*)&A[row * 128 + ((14 ^ (row & 15)) * 8)] = z;
        *(half8*)&A[row * 128 + ((15 ^ (row & 15)) * 8)] = z;
    }

    half8 B0[16];
#pragma unroll
    for (int i = 0; i < 16; ++i)
        B0[i] = *(const half8*)(fragTab + ((size_t)i * 64 + lane) * 8);
    float mb0v[4], mb1v[4], w2v[4];
#pragma unroll
    for (int nt = 0; nt < 4; ++nt) {
        mb0v[nt] = mb0[nt * 16 + n_];
        mb1v[nt] = mb1[nt * 16 + n_];
        w2v[nt]  = mw2[nt * 16 + n_];
    }
    const float mb2s = mb2[0];

    __syncthreads();

    {
        const int grp = tid >> 4;
        const int l   = tid & 15;
#pragma unroll 1
        for (int it = 0; it < 8; ++it) {
            const int row  = it * 16 + grp;
            const int base = pixL[row];
            float4v v = *(const float4v*)(aspp + base + l * 4);
            half4v h;
            h[0] = (_Float16)v[0]; h[1] = (_Float16)v[1];
            h[2] = (_Float16)v[2]; h[3] = (_Float16)v[3];
            *(half4v*)&A[row * 128 + (((l >> 1) ^ (row & 15)) * 8) + (l & 1) * 4] = h;
            if (l < 8) {
                const int qt = 16 + l;
                float4v v2 = *(const float4v*)(aspp + base + qt * 4);
                half4v h2;
                h2[0] = (_Float16)v2[0]; h2[1] = (_Float16)v2[1];
                h2[2] = (_Float16)v2[2]; h2[3] = (_Float16)v2[3];
                *(half4v*)&A[row * 128 + (((qt >> 1) ^ (row & 15)) * 8) + (qt & 1) * 4] = h2;
            }
        }
    }
    __syncthreads();

#pragma unroll 1
    for (int mt = 0; mt < 2; ++mt) {
        const int m0  = wv * 32 + mt * 16;
        const int row = m0 + n_;

        float4v acc[4];
#pragma unroll
        for (int nt = 0; nt < 4; ++nt) {
            float4v t = {mb0v[nt], mb0v[nt], mb0v[nt], mb0v[nt]};
            acc[nt] = t;
        }
#pragma unroll
        for (int kc = 0; kc < 4; ++kc) {
            half8 a = *(const half8*)&A[row * 128 + (((kc * 4 + qd) ^ (row & 15)) * 8)];
#pragma unroll
            for (int nt = 0; nt < 4; ++nt)
                acc[nt] = __builtin_amdgcn_mfma_f32_16x16x32_f16(a, B0[kc * 4 + nt],
                                                                 acc[nt], 0, 0, 0);
        }
#pragma unroll
        for (int nt = 0; nt < 4; ++nt)
#pragma unroll
            for (int reg = 0; reg < 4; ++reg) {
                const int hr = m0 + qd * 4 + reg;
                const int n  = nt * 16 + n_;
                Hb[hr * 64 + (((n >> 3) ^ (hr & 7)) * 8) + (n & 7)] =
                    (_Float16)fmaxf(acc[nt][reg], 0.f);
            }
        __builtin_amdgcn_s_waitcnt(0);

        float4v acc1[4];
#pragma unroll
        for (int nt = 0; nt < 4; ++nt) {
            float4v t = {mb1v[nt], mb1v[nt], mb1v[nt], mb1v[nt]};
            acc1[nt] = t;
        }
#pragma unroll
        for (int kc = 0; kc < 2; ++kc) {
            half8 a1 = *(const half8*)&Hb[row * 64 + (((kc * 4 + qd) ^ (row & 7)) * 8)];
#pragma unroll
            for (int nt = 0; nt < 4; ++nt) {
                half8 b1 = *(const half8*)(fragTab +
                            ((size_t)(16 + kc * 4 + nt) * 64 + lane) * 8);
                acc1[nt] = __builtin_amdgcn_mfma_f32_16x16x32_f16(a1, b1,
                                                                  acc1[nt], 0, 0, 0);
            }
        }

        float p[4];
#pragma unroll
        for (int reg = 0; reg < 4; ++reg) {
            float s = 0.f;
#pragma unroll
            for (int nt = 0; nt < 4; ++nt)
                s = fmaf(fmaxf(acc1[nt][reg], 0.f), w2v[nt], s);
            s += __shfl_xor(s, 1, 64);
            s += __shfl_xor(s, 2, 64);
            s += __shfl_xor(s, 4, 64);
            s += __shfl_xor(s, 8, 64);
            p[reg] = s;
        }
        if (n_ == 0) {
            float4v pv = {p[0] + mb2s, p[1] + mb2s, p[2] + mb2s, p[3] + mb2s};
            *(float4v*)&predL[m0 + qd * 4] = pv;
        }
    }
    __syncthreads();

    if (tid < 32) {
        float4v pr = *(const float4v*)&predL[tid * 4];
        float4v ar = *(const float4v*)&areaL[tid * 4];
        float num = pr[0] * ar[3] + pr[1] * ar[2] + pr[2] * ar[1] + pr[3] * ar[0];
        float den = ar[0] + ar[1] + ar[2] + ar[3];
        out[blockIdx.x * 32 + tid] = num / den;
    }
}

// ---------------------------------------------------------------------------
extern "C" void kernel_launch(void* const* d_in, const int* in_sizes, int n_in,
                              void* d_out, int out_size, void* d_ws, size_t ws_size,
                              hipStream_t stream) {
    (void)in_sizes; (void)n_in; (void)out_size; (void)ws_size;
    const float* feats2  = (const float*)d_in[0];
    const float* feats4  = (const float*)d_in[1];
    const float* feats32 = (const float*)d_in[2];
    const float* coords  = (const float*)d_in[3];
    const float* cells   = (const float*)d_in[4];
    const float* w2  = (const float*)d_in[5];
    const float* b2  = (const float*)d_in[6];
    const float* w4  = (const float*)d_in[7];
    const float* b4  = (const float*)d_in[8];
    const float* w32 = (const float*)d_in[9];
    const float* b32 = (const float*)d_in[10];
    const float* wf  = (const float*)d_in[11];
    const float* bf  = (const float*)d_in[12];
    const float* mw0 = (const float*)d_in[13];
    const float* mb0 = (const float*)d_in[14];
    const float* mw1 = (const float*)d_in[15];
    const float* mb1 = (const float*)d_in[16];
    const float* mw2 = (const float*)d_in[17];
    const float* mb2 = (const float*)d_in[18];

    float* ws   = (float*)d_ws;
    float* a4s  = ws;                   // 2*96*96*32   = 589824
    float* a32s = a4s  + 589824;        // 2*24*24*32   = 36864
    float* xcat = a32s + 36864;         // 2*192*192*96 = 7077888
    float* aspp = xcat + 7077888;       // 7077888
    _Float16* fragTab  = (_Float16*)(aspp + 7077888);  // 12288 halfs
    _Float16* fragTabW = fragTab + 12288;              // 82944 halfs
    float* out  = (float*)d_out;

    prep_frags<<<6, 256, 0, stream>>>(mw0, mw1, fragTab);
    prep_fragsW<<<41, 256, 0, stream>>>(wf, fragTabW);
    conv1x1_relu<96><<<2304, 256, 0, stream>>>(feats4, w4, b4, a4s, 2 * 96 * 96);
    conv1x1_relu<160><<<144, 256, 0, stream>>>(feats32, w32, b32, a32s, 2 * 24 * 24);
    conv1x1_relu_into96<<<9216, 256, 0, stream>>>(feats2, w2, b2, xcat, 2 * HA * HA);
    upsample_into96_2<<<18432, 256, 0, stream>>>(a4s, a32s, xcat);
    conv3x3_mfma<<<dim3(12, 24, 2), 256, 0, stream>>>(xcat, fragTabW, bf, aspp);
    decoder_mlp_mfma<<<9216, 256, 0, stream>>>(aspp, coords, cells, fragTab,
                                               mb0, mb1, mw2, mb2, out);
}

// Round 7
// 306.071 us; speedup vs baseline: 9.1463x; 1.1474x over previous
//
#include <hip/hip_runtime.h>
#include <math.h>

// ---------------------------------------------------------------------------
// Decoder_82764019794508: LIIF-style decoder.
// R7: byte-diet + launch fusion. Decoder is random-gather bandwidth bound
// (R6: 333 MB TCC traffic @ 2 TB/s == dispatch time). Changes:
//   - aspp stored fp16 (identical bits into decoder MFMA; gather row 384->192B)
//   - xcat stored fp16 (identical bits into conv3x3 staging)
//   - prep kernels fused; conv1x1 a4s/a32s fused; xcat 3 slices fused
//   - 5 launches total. Decoder/conv3x3 MFMA structure unchanged from R5/R6.
// ---------------------------------------------------------------------------

#define HQ 384
#define HA 192

typedef _Float16 half8  __attribute__((ext_vector_type(8)));
typedef _Float16 half4v __attribute__((ext_vector_type(4)));
typedef float    float4v __attribute__((ext_vector_type(4)));

// ---- K0: pack ALL weights into per-lane MFMA B-fragments ------------------
// t < 1536:  MLP frags (f<16 layer0 K=128-padded; f>=16 layer1)
// t >= 1536: conv3x3 frags, step s=(tap*3+kc) (27 K-steps), nt=0..5
// B-operand lane map: n = lane&15, k = (lane>>4)*8 + j.
__global__ void prep_all(const float* __restrict__ mw0,
                         const float* __restrict__ mw1,
                         const float* __restrict__ wf,
                         _Float16* __restrict__ fragTab,
                         _Float16* __restrict__ fragTabW) {
    int t = blockIdx.x * 256 + threadIdx.x;
    if (t < 1536) {
        int f = t >> 6, L = t & 63;
        int n_ = L & 15, qd = L >> 4;
        _Float16 vals[8];
        if (f < 16) {
            int kc = f >> 2, nt = f & 3;
#pragma unroll
            for (int j = 0; j < 8; ++j) {
                int kk = kc * 32 + qd * 8 + j;
                vals[j] = (_Float16)((kk < 102) ? mw0[kk * 64 + nt * 16 + n_] : 0.f);
            }
        } else {
            int g = f - 16;
            int kc = g >> 2, nt = g & 3;
#pragma unroll
            for (int j = 0; j < 8; ++j) {
                int kk = kc * 32 + qd * 8 + j;
                vals[j] = (_Float16)mw1[kk * 64 + nt * 16 + n_];
            }
        }
#pragma unroll
        for (int j = 0; j < 8; ++j) fragTab[t * 8 + j] = vals[j];
    } else {
        int tw = t - 1536;
        if (tw >= 27 * 6 * 64) return;
        int s   = tw / 384;
        int rem = tw - s * 384;
        int nt  = rem >> 6;
        int L   = rem & 63;
        int n_  = L & 15, qd = L >> 4;
        int tap = s / 3, kc = s - tap * 3;
#pragma unroll
        for (int j = 0; j < 8; ++j) {
            int kch = kc * 32 + qd * 8 + j;
            fragTabW[tw * 8 + j] = (_Float16)wf[(tap * 96 + kch) * 96 + nt * 16 + n_];
        }
    }
}

// ---- K1: fused 1x1 convs for a4s (96->32) and a32s (160->32), fp32 out ----
__global__ void conv1x1_ab(const float* __restrict__ feats4,
                           const float* __restrict__ w4,
                           const float* __restrict__ b4,
                           const float* __restrict__ feats32,
                           const float* __restrict__ w32,
                           const float* __restrict__ b32,
                           float* __restrict__ a4s,
                           float* __restrict__ a32s) {
    int blk = blockIdx.x;
    if (blk < 2304) {
        int t = blk * 256 + threadIdx.x;
        int p = t >> 5, c = t & 31;
        const float* xr = feats4 + (size_t)p * 96;
        float acc = b4[c];
#pragma unroll
        for (int i = 0; i < 96; ++i) acc = fmaf(xr[i], w4[i * 32 + c], acc);
        a4s[(size_t)p * 32 + c] = fmaxf(acc, 0.f);
    } else {
        int t = (blk - 2304) * 256 + threadIdx.x;
        int p = t >> 5, c = t & 31;
        const float* xr = feats32 + (size_t)p * 160;
        float acc = b32[c];
#pragma unroll
        for (int i = 0; i < 160; ++i) acc = fmaf(xr[i], w32[i * 32 + c], acc);
        a32s[(size_t)p * 32 + c] = fmaxf(acc, 0.f);
    }
}

// ---- K2: build xcat (fp16), 3 slices selected by blockIdx.y ---------------
// y=0: conv1x1 feats2 (64->32)+ReLU; y=1: upsample a4s; y=2: upsample a32s
__global__ void build_xcat(const float* __restrict__ feats2,
                           const float* __restrict__ w2,
                           const float* __restrict__ b2,
                           const float* __restrict__ a4s,
                           const float* __restrict__ a32s,
                           _Float16* __restrict__ xcatH) {
    const int z = blockIdx.y;
    int t = blockIdx.x * 256 + threadIdx.x;
    int c = t & 31;
    int p = t >> 5;                    // pixel in [0, 2*192*192)

    if (z == 0) {
        const float* xr = feats2 + (size_t)p * 64;
        float acc = b2[c];
#pragma unroll
        for (int i = 0; i < 64; ++i) acc = fmaf(xr[i], w2[i * 32 + c], acc);
        xcatH[(size_t)p * 96 + c] = (_Float16)fmaxf(acc, 0.f);
        return;
    }

    const float* src = (z == 1) ? a4s : a32s;
    const int   S    = (z == 1) ? 96 : 24;
    const float inv  = (z == 1) ? 0.5f : 0.125f;
    const int   coff = (z == 1) ? 32 : 64;

    int x = p % HA;
    int r = p / HA;
    int y = r % HA;
    int b = r / HA;

    float u = ((float)y + 0.5f) * inv - 0.5f;
    float v = ((float)x + 0.5f) * inv - 0.5f;
    float fu = floorf(u), fv = floorf(v);
    float wu = u - fu, wv = v - fv;
    int y0 = (int)fu, x0 = (int)fv;
    int y1 = min(y0 + 1, S - 1);
    int x1 = min(x0 + 1, S - 1);
    y0 = max(y0, 0);
    x0 = max(x0, 0);

    const float* sb = src + (size_t)b * S * S * 32 + c;
    float v00 = sb[(y0 * S + x0) * 32];
    float v01 = sb[(y0 * S + x1) * 32];
    float v10 = sb[(y1 * S + x0) * 32];
    float v11 = sb[(y1 * S + x1) * 32];
    float t0 = v00 * (1.f - wu) + v10 * wu;
    float t1 = v01 * (1.f - wu) + v11 * wu;
    float o  = t0 * (1.f - wv) + t1 * wv;
    xcatH[(size_t)p * 96 + coff + c] = (_Float16)o;
}

// ---- K3: 3x3 conv 96->96 + bias + ReLU via fp16 MFMA, fp16 in/out ---------
// Tile: 16(x) x 8(y). 4 waves: wave = (yg=wv>>1)*4 y-rows x (nh=wv&1)*3 n-tiles
__launch_bounds__(256, 4)
__global__ void conv3x3_mfma(const _Float16* __restrict__ xH,
                             const _Float16* __restrict__ fragTabW,
                             const float* __restrict__ bias,
                             _Float16* __restrict__ yH) {
    __shared__ _Float16 lds[10 * 18 * 104];  // 37,440 B
    const int tid = threadIdx.x;
    const int lane = tid & 63;
    const int wv   = tid >> 6;
    const int n_   = lane & 15;
    const int qd   = lane >> 4;
    const int nh   = wv & 1;
    const int yg   = wv >> 1;
    const int bx0  = blockIdx.x * 16;
    const int by0  = blockIdx.y * 8;
    const int b    = blockIdx.z;

    // stage halo (10 x 18 x 96 halfs) via half8 units: 10*18*12 = 2160
    for (int idx = tid; idx < 2160; idx += 256) {
        int hy  = idx / 216;
        int rem = idx - hy * 216;
        int hx  = rem / 12;
        int cc  = rem - hx * 12;
        int gy = by0 + hy - 1, gx = bx0 + hx - 1;
        half8 v = {(_Float16)0.f, (_Float16)0.f, (_Float16)0.f, (_Float16)0.f,
                   (_Float16)0.f, (_Float16)0.f, (_Float16)0.f, (_Float16)0.f};
        if (gy >= 0 && gy < HA && gx >= 0 && gx < HA)
            v = *(const half8*)(xH + (((size_t)b * HA + gy) * HA + gx) * 96 + cc * 8);
        *(half8*)&lds[(hy * 18 + hx) * 104 + cc * 8] = v;
    }

    float bv[3];
#pragma unroll
    for (int j = 0; j < 3; ++j) bv[j] = bias[(nh * 3 + j) * 16 + n_];

    __syncthreads();

    float4v acc[4][3];
#pragma unroll
    for (int r = 0; r < 4; ++r)
#pragma unroll
        for (int j = 0; j < 3; ++j) {
            float4v z = {0.f, 0.f, 0.f, 0.f};
            acc[r][j] = z;
        }

#pragma unroll 1
    for (int ky = 0; ky < 3; ++ky)
#pragma unroll 1
        for (int kx = 0; kx < 3; ++kx) {
            const int tap = ky * 3 + kx;
#pragma unroll
            for (int kc = 0; kc < 3; ++kc) {
                const int s = tap * 3 + kc;
                half8 bf[3];
#pragma unroll
                for (int j = 0; j < 3; ++j)
                    bf[j] = *(const half8*)(fragTabW +
                            ((size_t)(s * 6 + nh * 3 + j) * 64 + lane) * 8);
#pragma unroll
                for (int r = 0; r < 4; ++r) {
                    const int yr = yg * 4 + r;
                    half8 a = *(const half8*)&lds[((yr + ky) * 18 + (n_ + kx)) * 104
                                                  + kc * 32 + qd * 8];
#pragma unroll
                    for (int j = 0; j < 3; ++j)
                        acc[r][j] = __builtin_amdgcn_mfma_f32_16x16x32_f16(
                            a, bf[j], acc[r][j], 0, 0, 0);
                }
            }
        }

    // epilogue: bias + ReLU, store fp16 (single rounding -> identical bits
    // to the decoder's previous on-the-fly cvt of the fp32 value)
#pragma unroll
    for (int r = 0; r < 4; ++r) {
        const int gy = by0 + yg * 4 + r;
#pragma unroll
        for (int j = 0; j < 3; ++j) {
            const int ch = (nh * 3 + j) * 16 + n_;
#pragma unroll
            for (int reg = 0; reg < 4; ++reg) {
                const int gx = bx0 + qd * 4 + reg;
                yH[(((size_t)b * HA + gy) * HA + gx) * 96 + ch] =
                    (_Float16)fmaxf(acc[r][j][reg] + bv[j], 0.f);
            }
        }
    }
}

// ---- K4: 4-corner gather + MLP ensemble via fp16 MFMA ---------------------
// Block: 256 threads = 128 rows = 32 queries x 4 corners. aspp is fp16:
// gather = 12 active lanes/row x half8 (192 B/row, 3 cache lines).
__launch_bounds__(256, 3)
__global__ void decoder_mlp_mfma(const _Float16* __restrict__ asppH,
                                 const float* __restrict__ coords,
                                 const float* __restrict__ cells,
                                 const _Float16* __restrict__ fragTab,
                                 const float* __restrict__ mb0,
                                 const float* __restrict__ mb1,
                                 const float* __restrict__ mw2,
                                 const float* __restrict__ mb2,
                                 float* __restrict__ out) {
    __shared__ __align__(16) unsigned char smem[50688];
    _Float16* A   = (_Float16*)smem;              // 32768 B
    _Float16* Hb  = (_Float16*)(smem + 32768);    // 16384 B
    int*      pixL  = (int*)(smem + 49152);       // 512 B
    float*    areaL = (float*)(smem + 49664);     // 512 B
    float*    predL = (float*)(smem + 50176);     // 512 B

    const int tid  = threadIdx.x;
    const int lane = tid & 63;
    const int wv   = tid >> 6;
    const int n_   = lane & 15;
    const int qd   = lane >> 4;

    if (tid < 128) {
        const int lq = tid >> 2, k = tid & 3;
        const int q  = blockIdx.x * 32 + lq;
        const int b  = q / (HQ * HQ);
        const float cy = coords[(size_t)q * 2 + 0];
        const float cx = coords[(size_t)q * 2 + 1];
        const float rcy = cells[(size_t)q * 2 + 0] * (float)HA;
        const float rcx = cells[(size_t)q * 2 + 1] * (float)HA;

        const float LO = -1.0f + 1e-7f, HI = 1.0f - 1e-7f;
        const float RXY = 1.0f / (float)HA;
        const float vy = (k < 2) ? -1.f : 1.f;
        const float vx = (k & 1) ? 1.f : -1.f;

        float c0 = fminf(fmaxf((cy + vy * RXY) + 1e-7f, LO), HI);
        float c1 = fminf(fmaxf((cx + vx * RXY) + 1e-7f, LO), HI);
        int iy = (int)rintf(((c0 + 1.f) * (float)HA) * 0.5f - 0.5f);
        int ix = (int)rintf(((c1 + 1.f) * (float)HA) * 0.5f - 0.5f);
        iy = min(max(iy, 0), HA - 1);
        ix = min(max(ix, 0), HA - 1);

        const float cs0 = (((float)iy + 0.5f) / (float)HA) * 2.f - 1.f;
        const float cs1 = (((float)ix + 0.5f) / (float)HA) * 2.f - 1.f;
        const float r0 = (cy - cs0) * (float)HA;
        const float r1 = (cx - cs1) * (float)HA;

        pixL[tid]  = ((b * HA + iy) * HA + ix) * 96;   // half-element offset
        areaL[tid] = fabsf(r0 * r1) + 1e-7f;

        const int row = tid;
        half8 e0;
        e0[0] = (_Float16)r0;  e0[1] = (_Float16)r1;
        e0[2] = (_Float16)cy;  e0[3] = (_Float16)cx;
        e0[4] = (_Float16)rcy; e0[5] = (_Float16)rcx;
        e0[6] = (_Float16)0.f; e0[7] = (_Float16)0.f;
        half8 z = {(_Float16)0.f, (_Float16)0.f, (_Float16)0.f, (_Float16)0.f,
                   (_Float16)0.f, (_Float16)0.f, (_Float16)0.f, (_Float16)0.f};
        *(half8*)&A[row * 128 + ((12 ^ (row & 15)) * 8)] = e0;
        *(half8*)&A[row * 128 + ((13 ^ (row & 15)) * 8)] = z;
        *(half8*)&A[row * 128 + ((14 ^ (row & 15)) * 8)] = z;
        *(half8*)&A[row * 128 + ((15 ^ (row & 15)) * 8)] = z;
    }

    half8 B0[16];
#pragma unroll
    for (int i = 0; i < 16; ++i)
        B0[i] = *(const half8*)(fragTab + ((size_t)i * 64 + lane) * 8);
    float mb0v[4], mb1v[4], w2v[4];
#pragma unroll
    for (int nt = 0; nt < 4; ++nt) {
        mb0v[nt] = mb0[nt * 16 + n_];
        mb1v[nt] = mb1[nt * 16 + n_];
        w2v[nt]  = mw2[nt * 16 + n_];
    }
    const float mb2s = mb2[0];

    __syncthreads();

    // gather: 16-lane groups, lanes 0..11 load one half8 each (192 B/row)
    {
        const int grp = tid >> 4;
        const int l   = tid & 15;
#pragma unroll 1
        for (int it = 0; it < 8; ++it) {
            const int row  = it * 16 + grp;
            const int base = pixL[row];
            if (l < 12) {
                half8 h = *(const half8*)(asppH + base + l * 8);
                *(half8*)&A[row * 128 + ((l ^ (row & 15)) * 8)] = h;
            }
        }
    }
    __syncthreads();

#pragma unroll 1
    for (int mt = 0; mt < 2; ++mt) {
        const int m0  = wv * 32 + mt * 16;
        const int row = m0 + n_;

        float4v acc[4];
#pragma unroll
        for (int nt = 0; nt < 4; ++nt) {
            float4v t = {mb0v[nt], mb0v[nt], mb0v[nt], mb0v[nt]};
            acc[nt] = t;
        }
#pragma unroll
        for (int kc = 0; kc < 4; ++kc) {
            half8 a = *(const half8*)&A[row * 128 + (((kc * 4 + qd) ^ (row & 15)) * 8)];
#pragma unroll
            for (int nt = 0; nt < 4; ++nt)
                acc[nt] = __builtin_amdgcn_mfma_f32_16x16x32_f16(a, B0[kc * 4 + nt],
                                                                 acc[nt], 0, 0, 0);
        }
#pragma unroll
        for (int nt = 0; nt < 4; ++nt)
#pragma unroll
            for (int reg = 0; reg < 4; ++reg) {
                const int hr = m0 + qd * 4 + reg;
                const int n  = nt * 16 + n_;
                Hb[hr * 64 + (((n >> 3) ^ (hr & 7)) * 8) + (n & 7)] =
                    (_Float16)fmaxf(acc[nt][reg], 0.f);
            }
        __builtin_amdgcn_s_waitcnt(0);

        float4v acc1[4];
#pragma unroll
        for (int nt = 0; nt < 4; ++nt) {
            float4v t = {mb1v[nt], mb1v[nt], mb1v[nt], mb1v[nt]};
            acc1[nt] = t;
        }
#pragma unroll
        for (int kc = 0; kc < 2; ++kc) {
            half8 a1 = *(const half8*)&Hb[row * 64 + (((kc * 4 + qd) ^ (row & 7)) * 8)];
#pragma unroll
            for (int nt = 0; nt < 4; ++nt) {
                half8 b1 = *(const half8*)(fragTab +
                            ((size_t)(16 + kc * 4 + nt) * 64 + lane) * 8);
                acc1[nt] = __builtin_amdgcn_mfma_f32_16x16x32_f16(a1, b1,
                                                                  acc1[nt], 0, 0, 0);
            }
        }

        float p[4];
#pragma unroll
        for (int reg = 0; reg < 4; ++reg) {
            float s = 0.f;
#pragma unroll
            for (int nt = 0; nt < 4; ++nt)
                s = fmaf(fmaxf(acc1[nt][reg], 0.f), w2v[nt], s);
            s += __shfl_xor(s, 1, 64);
            s += __shfl_xor(s, 2, 64);
            s += __shfl_xor(s, 4, 64);
            s += __shfl_xor(s, 8, 64);
            p[reg] = s;
        }
        if (n_ == 0) {
            float4v pv = {p[0] + mb2s, p[1] + mb2s, p[2] + mb2s, p[3] + mb2s};
            *(float4v*)&predL[m0 + qd * 4] = pv;
        }
    }
    __syncthreads();

    if (tid < 32) {
        float4v pr = *(const float4v*)&predL[tid * 4];
        float4v ar = *(const float4v*)&areaL[tid * 4];
        float num = pr[0] * ar[3] + pr[1] * ar[2] + pr[2] * ar[1] + pr[3] * ar[0];
        float den = ar[0] + ar[1] + ar[2] + ar[3];
        out[blockIdx.x * 32 + tid] = num / den;
    }
}

// ---------------------------------------------------------------------------
extern "C" void kernel_launch(void* const* d_in, const int* in_sizes, int n_in,
                              void* d_out, int out_size, void* d_ws, size_t ws_size,
                              hipStream_t stream) {
    (void)in_sizes; (void)n_in; (void)out_size; (void)ws_size;
    const float* feats2  = (const float*)d_in[0];
    const float* feats4  = (const float*)d_in[1];
    const float* feats32 = (const float*)d_in[2];
    const float* coords  = (const float*)d_in[3];
    const float* cells   = (const float*)d_in[4];
    const float* w2  = (const float*)d_in[5];
    const float* b2  = (const float*)d_in[6];
    const float* w4  = (const float*)d_in[7];
    const float* b4  = (const float*)d_in[8];
    const float* w32 = (const float*)d_in[9];
    const float* b32 = (const float*)d_in[10];
    const float* wf  = (const float*)d_in[11];
    const float* bf  = (const float*)d_in[12];
    const float* mw0 = (const float*)d_in[13];
    const float* mb0 = (const float*)d_in[14];
    const float* mw1 = (const float*)d_in[15];
    const float* mb1 = (const float*)d_in[16];
    const float* mw2 = (const float*)d_in[17];
    const float* mb2 = (const float*)d_in[18];

    float* ws   = (float*)d_ws;
    float*    a4s   = ws;                          // 2*96*96*32 f
    float*    a32s  = a4s + 589824;                // 2*24*24*32 f
    _Float16* xcatH = (_Float16*)(a32s + 36864);   // 7,077,888 halfs
    _Float16* asppH = xcatH + 7077888;             // 7,077,888 halfs
    _Float16* fragTab  = asppH + 7077888;          // 12,288 halfs
    _Float16* fragTabW = fragTab + 12288;          // 82,944 halfs
    float* out  = (float*)d_out;

    prep_all<<<47, 256, 0, stream>>>(mw0, mw1, wf, fragTab, fragTabW);
    conv1x1_ab<<<2448, 256, 0, stream>>>(feats4, w4, b4, feats32, w32, b32,
                                         a4s, a32s);
    build_xcat<<<dim3(9216, 3), 256, 0, stream>>>(feats2, w2, b2, a4s, a32s,
                                                  xcatH);
    conv3x3_mfma<<<dim3(12, 24, 2), 256, 0, stream>>>(xcatH, fragTabW, bf, asppH);
    decoder_mlp_mfma<<<9216, 256, 0, stream>>>(asppH, coords, cells, fragTab,
                                               mb0, mb1, mw2, mb2, out);
}